// Round 12
// baseline (658.760 us; speedup 1.0000x reference)
//
#include <hip/hip_runtime.h>
#include <math.h>

#define G 20000
#define E_EDGES 640000
#define HID 64
#define NHEAD 4
#define BATCH 128
#define PD 600
#define NEG 0.2f
#define MAXE 256

#define KA1 20096          // 20064 padded to multiple of 32
#define NSTEP1 628         // 20096 / 32
#define KSPLIT1 32
#define KA2 1024

#define ROWS_HC 16         // rows per k_hc block: 1250 blocks (20000/16 exact)

typedef float v4f __attribute__((ext_vector_type(4)));
typedef short short8 __attribute__((ext_vector_type(8)));

__device__ __forceinline__ float sigmoidf_(float x){ return 1.0f/(1.0f+__expf(-x)); }
__device__ __forceinline__ float leakyf_(float x){ return x>=0.f ? x : NEG*x; }
__device__ __forceinline__ unsigned short f2bf(float f){
    unsigned int u = __float_as_uint(f);
    return (unsigned short)((u + 0x7FFFu + ((u >> 16) & 1u)) >> 16);
}
__device__ __forceinline__ float bf2f(unsigned short b){
    return __uint_as_float(((unsigned int)b) << 16);
}

// ---------- Stage 1 fused: hc/es/ed.  ROWS_HC rows/block, 320 threads. ----------
// R7: LDS eliminated. Old: 16 ds_read_b128/row/thread re-broadcasting the same row
// (82us, DS-pipe bound: 24 waves/CU x 16 rows x ~260 DS cyc ~ obs). New: row vector
// is wave-uniform -> uniform-address loads compile to s_load into SGPRs (per-block
// fetch, scalar cache), 65 v_fmac with SGPR operand, 4 accumulators. No barrier.
__global__ __launch_bounds__(320)
void k_hc(const float* __restrict__ x, const int* __restrict__ pos,
          const float* __restrict__ ge, const float* __restrict__ Wc,
          const float* __restrict__ Wl, const float* __restrict__ as_,
          const float* __restrict__ ad_,
          unsigned short* __restrict__ hcb, float* __restrict__ hlin,
          float* __restrict__ es, float* __restrict__ ed)
{
    int t = threadIdx.x;                 // 320
    int rb = blockIdx.x * ROWS_HC;       // grid 1250
    float wcol[65];
    if (t < 256){
        #pragma unroll
        for (int k = 0; k < 65; ++k) wcol[k] = Wc[k*256 + t];
    } else {
        int c = t - 256;
        #pragma unroll
        for (int k = 0; k < 65; ++k) wcol[k] = Wl[k*64 + c];
    }
    float a_s = 0.f, a_d = 0.f;
    if (t < 256){ a_s = as_[t]; a_d = ad_[t]; }

    #pragma unroll 2
    for (int r = 0; r < ROWS_HC; ++r){
        int row = rb + r;                // wave-uniform
        float xv = x[row];               // uniform -> s_load
        int p   = pos[row];              // uniform -> s_load
        const float4* gr = (const float4*)(ge + (size_t)p * HID);
        float a0 = xv * wcol[0], a1 = 0.f, a2 = 0.f, a3 = 0.f;
        #pragma unroll
        for (int k4 = 0; k4 < 16; ++k4){
            float4 g = gr[k4];           // uniform -> s_load_dwordx4
            a0 += g.x * wcol[4*k4+1];
            a1 += g.y * wcol[4*k4+2];
            a2 += g.z * wcol[4*k4+3];
            a3 += g.w * wcol[4*k4+4];
        }
        float acc = (a0 + a1) + (a2 + a3);
        if (t < 256){
            hcb[(size_t)row*256 + t] = f2bf(acc);
            float v1 = acc * a_s, v2 = acc * a_d;
            #pragma unroll
            for (int m = 32; m; m >>= 1){ v1 += __shfl_xor(v1, m); v2 += __shfl_xor(v2, m); }
            if ((t & 63) == 0){ int h = t >> 6; es[row*4+h] = v1; ed[row*4+h] = v2; }
        } else {
            hlin[(size_t)row*64 + (t - 256)] = acc;
        }
    }
}

// ---------- CSR build ----------
__global__ void k_hist(const int* __restrict__ ei, int* __restrict__ cnt){
    int e = blockIdx.x*blockDim.x + threadIdx.x;
    if (e < E_EDGES) atomicAdd(&cnt[ei[E_EDGES + e]], 1);
}
__global__ void k_scan(const int* __restrict__ cnt, int* __restrict__ offs,
                       int* __restrict__ cur)
{
    __shared__ int ts[1024];
    int t = threadIdx.x;
    int base = t * 20;
    int loc[20];
    int s = 0;
    #pragma unroll
    for (int j = 0; j < 20; ++j){
        int i = base + j;
        int v = (i < G) ? cnt[i] : 0;
        loc[j] = s; s += v;
    }
    ts[t] = s;
    __syncthreads();
    for (int off = 1; off < 1024; off <<= 1){
        int add = (t >= off) ? ts[t - off] : 0;
        __syncthreads();
        ts[t] += add;
        __syncthreads();
    }
    int tb = (t == 0) ? 0 : ts[t - 1];
    #pragma unroll
    for (int j = 0; j < 20; ++j){
        int i = base + j;
        if (i < G){ int o = tb + loc[j]; offs[i] = o; cur[i] = o; }
    }
    if (t == 0) offs[G] = ts[1023];
}
__global__ void k_scatter(const int* __restrict__ ei, int* __restrict__ cur, int* __restrict__ csr){
    int e = blockIdx.x*blockDim.x + threadIdx.x;
    if (e < E_EDGES){
        int d = ei[E_EDGES + e];
        int p = atomicAdd(&cur[d], 1);
        csr[p] = ei[e];
    }
}

// ---------- GAT1 apply: softmax + bf16 gather SpMM + head-mean + lin1 + sigmoid ----------
// R5: wave g loads row ssrc[base+g] as 64 x uint2 (8B/lane), 1-deep prefetch.
// Lane u owns flat cols 4u..4u+3 (head u>>4). Wave-uniform loop bound, no divergence.
__global__ __launch_bounds__(256)
void k_gat1(const unsigned short* __restrict__ hcb, const float* __restrict__ hlin,
            const float* __restrict__ es, const float* __restrict__ ed,
            const int* __restrict__ offs, const int* __restrict__ csr,
            const float* __restrict__ bc1, const float* __restrict__ bl1,
            float* __restrict__ h1)
{
    int d = blockIdx.x; int t = threadIdx.x; // 256
    int lane = t & 63, wv = t >> 6;
    __shared__ float4 cache[MAXE];
    __shared__ int    ssrc[MAXE];
    __shared__ float  wredm[4][4];
    __shared__ float  wreds[4][4];
    __shared__ float4 red[256];
    int o = offs[d];
    int deg = offs[d+1] - o;
    int total = deg + 1;              // + self loop
    if (total > MAXE) total = MAXE;
    float4 edv = *(const float4*)(ed + d*4);
    float mx0=-1e30f, mx1=-1e30f, mx2=-1e30f, mx3=-1e30f;
    for (int idx = t; idx < total; idx += 256){
        int s = (idx < deg) ? csr[o + idx] : d;
        ssrc[idx] = s;
        float4 ev = *(const float4*)(es + s*4);
        float e0 = leakyf_(ev.x + edv.x);
        float e1 = leakyf_(ev.y + edv.y);
        float e2 = leakyf_(ev.z + edv.z);
        float e3 = leakyf_(ev.w + edv.w);
        cache[idx] = make_float4(e0, e1, e2, e3);
        mx0 = fmaxf(mx0, e0); mx1 = fmaxf(mx1, e1);
        mx2 = fmaxf(mx2, e2); mx3 = fmaxf(mx3, e3);
    }
    #pragma unroll
    for (int m = 32; m; m >>= 1){
        mx0 = fmaxf(mx0, __shfl_xor(mx0, m)); mx1 = fmaxf(mx1, __shfl_xor(mx1, m));
        mx2 = fmaxf(mx2, __shfl_xor(mx2, m)); mx3 = fmaxf(mx3, __shfl_xor(mx3, m));
    }
    if (lane == 0){ wredm[wv][0]=mx0; wredm[wv][1]=mx1; wredm[wv][2]=mx2; wredm[wv][3]=mx3; }
    __syncthreads();
    float m0 = fmaxf(fmaxf(wredm[0][0], wredm[1][0]), fmaxf(wredm[2][0], wredm[3][0]));
    float m1 = fmaxf(fmaxf(wredm[0][1], wredm[1][1]), fmaxf(wredm[2][1], wredm[3][1]));
    float m2 = fmaxf(fmaxf(wredm[0][2], wredm[1][2]), fmaxf(wredm[2][2], wredm[3][2]));
    float m3 = fmaxf(fmaxf(wredm[0][3], wredm[1][3]), fmaxf(wredm[2][3], wredm[3][3]));
    float s0=0.f, s1=0.f, s2=0.f, s3=0.f;
    for (int idx = t; idx < total; idx += 256){
        float4 cv = cache[idx];
        float e0 = __expf(cv.x - m0);
        float e1 = __expf(cv.y - m1);
        float e2 = __expf(cv.z - m2);
        float e3 = __expf(cv.w - m3);
        cache[idx] = make_float4(e0, e1, e2, e3);
        s0 += e0; s1 += e1; s2 += e2; s3 += e3;
    }
    #pragma unroll
    for (int m = 32; m; m >>= 1){
        s0 += __shfl_xor(s0, m); s1 += __shfl_xor(s1, m);
        s2 += __shfl_xor(s2, m); s3 += __shfl_xor(s3, m);
    }
    if (lane == 0){ wreds[wv][0]=s0; wreds[wv][1]=s1; wreds[wv][2]=s2; wreds[wv][3]=s3; }
    __syncthreads();

    // ---- gather SpMM: wave wv handles neighbors base+wv; lane owns cols 4u..4u+3 ----
    int u = lane;
    int h = u >> 4;                    // head of this lane's col-quad
    float inv = 1.0f / (wreds[0][h] + wreds[1][h] + wreds[2][h] + wreds[3][h]);
    float a0=0.f, a1=0.f, a2=0.f, a3=0.f;
    uint2 v; float al;
    bool act = (wv < total);
    if (act){
        int s = ssrc[wv];
        al = ((const float*)&cache[wv])[h];
        v = *(const uint2*)(hcb + (size_t)s*256 + u*4);
    }
    for (int base = wv; base < total; ){
        uint2 vc = v; float ac = al;
        int nb = base + 4;
        if (nb < total){                 // wave-uniform
            int s2 = ssrc[nb];
            al = ((const float*)&cache[nb])[h];
            v = *(const uint2*)(hcb + (size_t)s2*256 + u*4);
        }
        a0 += ac * __uint_as_float(vc.x << 16);
        a1 += ac * __uint_as_float(vc.x & 0xFFFF0000u);
        a2 += ac * __uint_as_float(vc.y << 16);
        a3 += ac * __uint_as_float(vc.y & 0xFFFF0000u);
        base = nb;
    }
    red[t] = make_float4(a0*inv, a1*inv, a2*inv, a3*inv);
    __syncthreads();
    if (t < 64){
        float sum = 0.f;
        #pragma unroll
        for (int hh = 0; hh < 4; ++hh){
            int f = hh*64 + t;           // flat col
            int uu = f >> 2, slot = f & 3;
            #pragma unroll
            for (int g = 0; g < 4; ++g)
                sum += ((const float*)&red[g*64 + uu])[slot];
        }
        float val = 0.25f*sum + bc1[t] + hlin[(size_t)d*64 + t] + bl1[t];
        h1[d*64 + t] = sigmoidf_(val);
    }
}

// ---------- conv2 prep ----------
__global__ void k_conv2prep(const float* __restrict__ h1, const float* __restrict__ W2c,
                            const float* __restrict__ as2, const float* __restrict__ ad2,
                            const float* __restrict__ Wl2, float* __restrict__ hh2,
                            float* __restrict__ es2, float* __restrict__ ed2,
                            float* __restrict__ lv)
{
    int i = blockIdx.x; int k = threadIdx.x; // 64
    float hv = h1[i*64 + k];
    #pragma unroll
    for (int j = 0; j < 4; ++j){
        float v = hv * W2c[k*4 + j];
        for (int m = 32; m; m >>= 1) v += __shfl_xor(v, m);
        if (k == 0){ hh2[i*4+j] = v; es2[i*4+j] = v*as2[j]; ed2[i*4+j] = v*ad2[j]; }
    }
    float v = hv * Wl2[k];
    for (int m = 32; m; m >>= 1) v += __shfl_xor(v, m);
    if (k == 0) lv[i] = v;
}

// ---------- GAT2 apply ----------
__global__ void k_gat2(const float* __restrict__ hh2, const float* __restrict__ es2,
                       const float* __restrict__ ed2, const int* __restrict__ offs,
                       const int* __restrict__ csr, const float* __restrict__ lv,
                       const float* __restrict__ bc2, const float* __restrict__ bl2,
                       float* __restrict__ feat)
{
    int d = blockIdx.x; int j = threadIdx.x; // 64
    int o = offs[d];
    int deg = offs[d+1] - o;
    int total = deg + 1;
    float edst[4];
    #pragma unroll
    for (int h = 0; h < 4; ++h) edst[h] = ed2[d*4+h];
    float lmax[4] = {-1e30f,-1e30f,-1e30f,-1e30f};
    for (int idx = j; idx < total; idx += 64){
        int s = (idx < deg) ? csr[o + idx] : d;
        #pragma unroll
        for (int h = 0; h < 4; ++h)
            lmax[h] = fmaxf(lmax[h], leakyf_(es2[s*4+h] + edst[h]));
    }
    #pragma unroll
    for (int h = 0; h < 4; ++h)
        for (int m = 32; m; m >>= 1) lmax[h] = fmaxf(lmax[h], __shfl_xor(lmax[h], m));
    float lsum[4] = {0.f,0.f,0.f,0.f};
    float lnum[4] = {0.f,0.f,0.f,0.f};
    for (int idx = j; idx < total; idx += 64){
        int s = (idx < deg) ? csr[o + idx] : d;
        #pragma unroll
        for (int h = 0; h < 4; ++h){
            float e  = leakyf_(es2[s*4+h] + edst[h]);
            float ex = __expf(e - lmax[h]);
            lsum[h] += ex;
            lnum[h] += ex * hh2[s*4+h];
        }
    }
    #pragma unroll
    for (int h = 0; h < 4; ++h){
        for (int m = 32; m; m >>= 1){ lsum[h] += __shfl_xor(lsum[h], m); lnum[h] += __shfl_xor(lnum[h], m); }
    }
    if (j == 0){
        float sum = 0.f;
        #pragma unroll
        for (int h = 0; h < 4; ++h) sum += lnum[h] / lsum[h];
        feat[d] = sigmoidf_(0.25f*sum + bc2[0] + lv[d] + bl2[0]);
    }
}

// ---------- prep A1 (bf16, [row][k], row-major = ctrl's layout, no transpose) ----------
__global__ void k_prepA(const float* __restrict__ ctrl, const float* __restrict__ feat,
                        unsigned short* __restrict__ Abf)
{
    int col = blockIdx.x*256 + threadIdx.x;
    int row = blockIdx.y;
    if (col < 20000)
        Abf[(size_t)row*KA1 + col] = f2bf(ctrl[(size_t)row*20000 + col] + feat[col]);
}

// ---------- pert MLP -> writes Abf1 cols 20000..20063 (+ zero pad to 20095) ----------
__global__ void k_pert(const float* __restrict__ pert, const float* __restrict__ W1,
                       const float* __restrict__ b1, const float* __restrict__ W2,
                       const float* __restrict__ b2, unsigned short* __restrict__ Abf)
{
    int r = blockIdx.x; int t = threadIdx.x; // 128
    __shared__ float hid[128];
    float acc = 0.f;
    for (int k = 0; k < PD; ++k) acc += pert[r*PD + k] * W1[k*128 + t];
    hid[t] = sigmoidf_(acc + b1[t]);
    __syncthreads();
    if (t < 64){
        float a2 = 0.f;
        for (int k = 0; k < 128; ++k) a2 += hid[k] * W2[k*64 + t];
        Abf[(size_t)r*KA1 + 20000 + t] = f2bf(a2 + b2[t]);
    } else if (t < 96){
        Abf[(size_t)r*KA1 + 20000 + t] = 0;  // zero K-pad 20064..20095
    }
}

// ---------- pred GEMM1 (MFMA bf16): part[ks] = A[128 x Kchunk] @ W1 ----------
__global__ __launch_bounds__(256, 2)
void k_gemm1m(const unsigned short* __restrict__ Abf, const float* __restrict__ W1,
              float* __restrict__ part)
{
    int t = threadIdx.x;
    int lane = t & 63, wv = t >> 6;
    int lane16 = lane & 15, quad = lane >> 4, quad8 = quad * 8;
    int colbase = blockIdx.x * 64;
    int ks = blockIdx.y;
    int sbeg = (ks * NSTEP1) / KSPLIT1;
    int send = ((ks + 1) * NSTEP1) / KSPLIT1;
    int nsteps = send - sbeg;
    int kbeg = sbeg * 32;
    __shared__ unsigned short Bs[2][32*64];

    v4f acc[8];
    #pragma unroll
    for (int i = 0; i < 8; ++i) acc[i] = (v4f){0.f,0.f,0.f,0.f};

    int krow = t >> 3;           // 0..31
    int ng   = (t & 7) * 8;      // 0..56
    {
        int kg = kbeg + krow;
        short8 p;
        if (kg < 20064){
            float4 a = *(const float4*)(W1 + (size_t)kg*1024 + colbase + ng);
            float4 b = *(const float4*)(W1 + (size_t)kg*1024 + colbase + ng + 4);
            p[0]=(short)f2bf(a.x); p[1]=(short)f2bf(a.y); p[2]=(short)f2bf(a.z); p[3]=(short)f2bf(a.w);
            p[4]=(short)f2bf(b.x); p[5]=(short)f2bf(b.y); p[6]=(short)f2bf(b.z); p[7]=(short)f2bf(b.w);
        } else {
            p = (short8){0,0,0,0,0,0,0,0};
        }
        *(short8*)&Bs[0][krow*64 + ng] = p;
    }
    __syncthreads();

    int cur = 0;
    for (int s = 0; s < nsteps; ++s){
        int kg = kbeg + s*32;
        short8 bfrag;
        #pragma unroll
        for (int j = 0; j < 8; ++j)
            bfrag[j] = (short)Bs[cur][(quad8 + j)*64 + wv*16 + lane16];
        float w[8];
        bool more = (s + 1) < nsteps;
        if (more){
            int kn = kg + 32 + krow;
            if (kn < 20064){
                float4 a = *(const float4*)(W1 + (size_t)kn*1024 + colbase + ng);
                float4 b = *(const float4*)(W1 + (size_t)kn*1024 + colbase + ng + 4);
                w[0]=a.x; w[1]=a.y; w[2]=a.z; w[3]=a.w; w[4]=b.x; w[5]=b.y; w[6]=b.z; w[7]=b.w;
            } else {
                #pragma unroll
                for (int i = 0; i < 8; ++i) w[i] = 0.f;
            }
        }
        #pragma unroll
        for (int mt = 0; mt < 8; ++mt){
            short8 af = *(const short8*)(Abf + (size_t)(mt*16 + lane16)*KA1 + kg + quad8);
            acc[mt] = __builtin_amdgcn_mfma_f32_16x16x32_bf16(af, bfrag, acc[mt], 0, 0, 0);
        }
        if (more){
            short8 p;
            #pragma unroll
            for (int i = 0; i < 8; ++i) p[i] = (short)f2bf(w[i]);
            *(short8*)&Bs[cur^1][krow*64 + ng] = p;
        }
        __syncthreads();
        cur ^= 1;
    }
    float* dst = part + (size_t)ks * 131072;
    int col = colbase + wv*16 + lane16;
    #pragma unroll
    for (int mt = 0; mt < 8; ++mt)
        #pragma unroll
        for (int r = 0; r < 4; ++r)
            dst[(size_t)(mt*16 + quad*4 + r)*1024 + col] = acc[mt][r];
}

// ---------- reduce partials + bias + sigmoid -> hidbf[128][1024] bf16 ----------
__global__ void k_reduce(const float* __restrict__ part, const float* __restrict__ b1,
                         unsigned short* __restrict__ hidbf)
{
    int row = blockIdx.x;                       // 0..127
    int col = blockIdx.y*256 + threadIdx.x;     // 0..1023
    float s = 0.f;
    #pragma unroll
    for (int ks = 0; ks < KSPLIT1; ++ks)
        s += part[(size_t)ks*131072 + (size_t)row*1024 + col];
    hidbf[(size_t)row*1024 + col] = f2bf(sigmoidf_(s + b1[col]));
}

// ---------- pred GEMM2 (MFMA bf16): out = hid[128x1024] @ W2 + b2 ----------
__global__ __launch_bounds__(256, 2)
void k_gemm2m(const unsigned short* __restrict__ hidbf, const float* __restrict__ W2,
              const float* __restrict__ b2, float* __restrict__ out)
{
    int t = threadIdx.x;
    int lane = t & 63, wv = t >> 6;
    int lane16 = lane & 15, quad = lane >> 4, quad8 = quad * 8;
    int colbase = blockIdx.x * 64;
    int rbase   = blockIdx.y * 64;
    __shared__ unsigned short Bs[2][32*64];

    v4f acc[4];
    #pragma unroll
    for (int i = 0; i < 4; ++i) acc[i] = (v4f){0.f,0.f,0.f,0.f};

    int krow = t >> 3;
    int ng   = (t & 7) * 8;
    bool cv = (colbase + ng) < 20000;   // 8-col granule, 20000 % 8 == 0
    {
        short8 p = (short8){0,0,0,0,0,0,0,0};
        if (cv){
            float4 a = *(const float4*)(W2 + (size_t)krow*20000 + colbase + ng);
            float4 b = *(const float4*)(W2 + (size_t)krow*20000 + colbase + ng + 4);
            p[0]=(short)f2bf(a.x); p[1]=(short)f2bf(a.y); p[2]=(short)f2bf(a.z); p[3]=(short)f2bf(a.w);
            p[4]=(short)f2bf(b.x); p[5]=(short)f2bf(b.y); p[6]=(short)f2bf(b.z); p[7]=(short)f2bf(b.w);
        }
        *(short8*)&Bs[0][krow*64 + ng] = p;
    }
    __syncthreads();

    int cur = 0;
    for (int s = 0; s < 32; ++s){
        int kg = s*32;
        short8 bfrag;
        #pragma unroll
        for (int j = 0; j < 8; ++j)
            bfrag[j] = (short)Bs[cur][(quad8 + j)*64 + wv*16 + lane16];
        float w[8];
        bool more = s < 31;
        if (more){
            if (cv){
                int kn = kg + 32 + krow;
                float4 a = *(const float4*)(W2 + (size_t)kn*20000 + colbase + ng);
                float4 b = *(const float4*)(W2 + (size_t)kn*20000 + colbase + ng + 4);
                w[0]=a.x; w[1]=a.y; w[2]=a.z; w[3]=a.w; w[4]=b.x; w[5]=b.y; w[6]=b.z; w[7]=b.w;
            } else {
                #pragma unroll
                for (int i = 0; i < 8; ++i) w[i] = 0.f;
            }
        }
        #pragma unroll
        for (int mt = 0; mt < 4; ++mt){
            short8 af = *(const short8*)(hidbf + (size_t)(rbase + mt*16 + lane16)*KA2 + kg + quad8);
            acc[mt] = __builtin_amdgcn_mfma_f32_16x16x32_bf16(af, bfrag, acc[mt], 0, 0, 0);
        }
        if (more){
            short8 p;
            #pragma unroll
            for (int i = 0; i < 8; ++i) p[i] = (short)f2bf(w[i]);
            *(short8*)&Bs[cur^1][krow*64 + ng] = p;
        }
        __syncthreads();
        cur ^= 1;
    }
    int col = colbase + wv*16 + lane16;
    if (col < 20000){
        float bb = b2[col];
        #pragma unroll
        for (int mt = 0; mt < 4; ++mt)
            #pragma unroll
            for (int r = 0; r < 4; ++r)
                out[(size_t)(rbase + mt*16 + quad*4 + r)*20000 + col] = acc[mt][r] + bb;
    }
}

extern "C" void kernel_launch(void* const* d_in, const int* in_sizes, int n_in,
                              void* d_out, int out_size, void* d_ws, size_t ws_size,
                              hipStream_t stream)
{
    const float* x    = (const float*)d_in[0];
    const int*   ei   = (const int*)  d_in[1];
    const int*   pos  = (const int*)  d_in[2];
    const float* ctrl = (const float*)d_in[3];
    const float* pert = (const float*)d_in[4];
    const float* ge   = (const float*)d_in[5];
    const float* c1W  = (const float*)d_in[6];
    const float* c1as = (const float*)d_in[7];
    const float* c1ad = (const float*)d_in[8];
    const float* c1b  = (const float*)d_in[9];
    const float* l1W  = (const float*)d_in[10];
    const float* l1b  = (const float*)d_in[11];
    const float* c2W  = (const float*)d_in[12];
    const float* c2as = (const float*)d_in[13];
    const float* c2ad = (const float*)d_in[14];
    const float* c2b  = (const float*)d_in[15];
    const float* l2W  = (const float*)d_in[16];
    const float* l2b  = (const float*)d_in[17];
    const float* pW1  = (const float*)d_in[18];
    const float* pb1  = (const float*)d_in[19];
    const float* pW2  = (const float*)d_in[20];
    const float* pb2  = (const float*)d_in[21];
    const float* prW1 = (const float*)d_in[22];
    const float* prb1 = (const float*)d_in[23];
    const float* prW2 = (const float*)d_in[24];
    const float* prb2 = (const float*)d_in[25];
    float* out = (float*)d_out;

    char* ws = (char*)d_ws;
    size_t off = 0;
    auto alloc = [&](size_t bytes)->void*{
        void* pp = ws + off;
        off += (bytes + 255) & ~(size_t)255;
        return pp;
    };
    unsigned short* hcb  = (unsigned short*)alloc((size_t)G*256*2);  // 10.24 MB
    float* hlin = (float*)alloc((size_t)G*64*4);                      // 5.12 MB
    float* h1   = (float*)alloc((size_t)G*64*4);
    float* es1  = (float*)alloc((size_t)G*4*4);
    float* ed1  = (float*)alloc((size_t)G*4*4);
    float* hh2  = (float*)alloc((size_t)G*4*4);
    float* es2  = (float*)alloc((size_t)G*4*4);
    float* ed2  = (float*)alloc((size_t)G*4*4);
    float* lv   = (float*)alloc((size_t)G*4);
    float* feat = (float*)alloc((size_t)G*4);
    unsigned short* hidbf = (unsigned short*)alloc((size_t)128*KA2*2);
    unsigned short* Abf1  = (unsigned short*)alloc((size_t)128*KA1*2);   // 5.1 MB
    float* part = (float*)alloc((size_t)KSPLIT1*131072*4);               // 16.8 MB
    int*   cnt  = (int*)alloc((size_t)G*4);
    int*   offs = (int*)alloc((size_t)(G+1)*4);
    int*   cur  = (int*)alloc((size_t)G*4);
    int*   csr  = (int*)alloc((size_t)E_EDGES*4);

    hipMemsetAsync(cnt, 0, (size_t)G*4, stream);

    k_hist   <<<(E_EDGES+255)/256, 256, 0, stream>>>(ei, cnt);
    k_scan   <<<1, 1024, 0, stream>>>(cnt, offs, cur);
    k_scatter<<<(E_EDGES+255)/256, 256, 0, stream>>>(ei, cur, csr);

    k_hc       <<<(G + ROWS_HC - 1)/ROWS_HC, 320, 0, stream>>>(x, pos, ge, c1W, l1W, c1as, c1ad,
                                         hcb, hlin, es1, ed1);
    k_gat1     <<<G, 256, 0, stream>>>(hcb, hlin, es1, ed1, offs, csr, c1b, l1b, h1);
    k_conv2prep<<<G, 64, 0, stream>>>(h1, c2W, c2as, c2ad, l2W, hh2, es2, ed2, lv);
    k_gat2     <<<G, 64, 0, stream>>>(hh2, es2, ed2, offs, csr, lv, c2b, l2b, feat);

    dim3 gp(79, 128);
    k_prepA<<<gp, 256, 0, stream>>>(ctrl, feat, Abf1);
    k_pert <<<BATCH, 128, 0, stream>>>(pert, pW1, pb1, pW2, pb2, Abf1);

    dim3 g1(16, KSPLIT1);
    k_gemm1m<<<g1, 256, 0, stream>>>(Abf1, prW1, part);
    dim3 gr(128, 4);
    k_reduce<<<gr, 256, 0, stream>>>(part, prb1, hidbf);
    dim3 g2(313, 2);
    k_gemm2m<<<g2, 256, 0, stream>>>(hidbf, prW2, prb2, out);
}

// Round 14
// 605.669 us; speedup vs baseline: 1.0877x; 1.0877x over previous
//
#include <hip/hip_runtime.h>
#include <math.h>

#define G 20000
#define E_EDGES 640000
#define HID 64
#define NHEAD 4
#define BATCH 128
#define PD 600
#define NEG 0.2f
#define MAXN 128           // per-dst neighbor cap (deg ~ Poisson(32), max ~70)

#define KA1 20096          // 20064 padded to multiple of 32
#define NSTEP1 628         // 20096 / 32
#define KSPLIT1 32
#define KA2 1024

#define ROWS_HC 16         // rows per k_hc block: 1250 blocks (R5-verified config, 82us)

typedef float v4f __attribute__((ext_vector_type(4)));
typedef short short8 __attribute__((ext_vector_type(8)));

__device__ __forceinline__ float sigmoidf_(float x){ return 1.0f/(1.0f+__expf(-x)); }
__device__ __forceinline__ float leakyf_(float x){ return x>=0.f ? x : NEG*x; }
__device__ __forceinline__ unsigned short f2bf(float f){
    unsigned int u = __float_as_uint(f);
    return (unsigned short)((u + 0x7FFFu + ((u >> 16) & 1u)) >> 16);
}
__device__ __forceinline__ float bf2f(unsigned short b){
    return __uint_as_float(((unsigned int)b) << 16);
}

// ---------- Stage 1 fused: hc/es/ed.  ROWS_HC rows/block, 320 threads. ----------
// R12: REVERTED to R5-verified LDS version (82us). R7 scalar-load variant regressed
// to 122us: per-wave duplicated s_load chains (FETCH 3.0->5.5MB, VALUBusy 26->14%).
__global__ __launch_bounds__(320)
void k_hc(const float* __restrict__ x, const int* __restrict__ pos,
          const float* __restrict__ ge, const float* __restrict__ Wc,
          const float* __restrict__ Wl, const float* __restrict__ as_,
          const float* __restrict__ ad_,
          unsigned short* __restrict__ hcb, float* __restrict__ hlin,
          float* __restrict__ es, float* __restrict__ ed)
{
    int t = threadIdx.x;                 // 320
    int rb = blockIdx.x * ROWS_HC;       // grid 1250
    __shared__ float xc[ROWS_HC][68];    // row stride 272B (16B aligned)
    for (int l = t; l < ROWS_HC*65; l += 320){
        int r = l / 65, k = l - r*65;
        int row = rb + r;
        float v = 0.f;
        if (row < G) v = (k == 0) ? x[row] : ge[pos[row]*HID + (k-1)];
        xc[r][k] = v;
    }
    float wcol[65];
    if (t < 256){
        #pragma unroll
        for (int k = 0; k < 65; ++k) wcol[k] = Wc[k*256 + t];
    } else {
        int c = t - 256;
        #pragma unroll
        for (int k = 0; k < 65; ++k) wcol[k] = Wl[k*64 + c];
    }
    float a_s = 0.f, a_d = 0.f;
    if (t < 256){ a_s = as_[t]; a_d = ad_[t]; }
    __syncthreads();

    int nrow = G - rb; if (nrow > ROWS_HC) nrow = ROWS_HC;
    for (int r = 0; r < nrow; ++r){
        int row = rb + r;
        const float4* xr = (const float4*)&xc[r][0];
        float acc = 0.f;
        #pragma unroll
        for (int k4 = 0; k4 < 16; ++k4){
            float4 v = xr[k4];
            acc += v.x*wcol[4*k4] + v.y*wcol[4*k4+1] + v.z*wcol[4*k4+2] + v.w*wcol[4*k4+3];
        }
        acc += xc[r][64] * wcol[64];
        if (t < 256){
            hcb[(size_t)row*256 + t] = f2bf(acc);
            float v1 = acc * a_s, v2 = acc * a_d;
            #pragma unroll
            for (int m = 32; m; m >>= 1){ v1 += __shfl_xor(v1, m); v2 += __shfl_xor(v2, m); }
            if ((t & 63) == 0){ int h = t >> 6; es[row*4+h] = v1; ed[row*4+h] = v2; }
        } else {
            hlin[(size_t)row*64 + (t - 256)] = acc;
        }
    }
}

// ---------- CSR build ----------
__global__ void k_hist(const int* __restrict__ ei, int* __restrict__ cnt){
    int e = blockIdx.x*blockDim.x + threadIdx.x;
    if (e < E_EDGES) atomicAdd(&cnt[ei[E_EDGES + e]], 1);
}
__global__ void k_scan(const int* __restrict__ cnt, int* __restrict__ offs,
                       int* __restrict__ cur)
{
    __shared__ int ts[1024];
    int t = threadIdx.x;
    int base = t * 20;
    int loc[20];
    int s = 0;
    #pragma unroll
    for (int j = 0; j < 20; ++j){
        int i = base + j;
        int v = (i < G) ? cnt[i] : 0;
        loc[j] = s; s += v;
    }
    ts[t] = s;
    __syncthreads();
    for (int off = 1; off < 1024; off <<= 1){
        int add = (t >= off) ? ts[t - off] : 0;
        __syncthreads();
        ts[t] += add;
        __syncthreads();
    }
    int tb = (t == 0) ? 0 : ts[t - 1];
    #pragma unroll
    for (int j = 0; j < 20; ++j){
        int i = base + j;
        if (i < G){ int o = tb + loc[j]; offs[i] = o; cur[i] = o; }
    }
    if (t == 0) offs[G] = ts[1023];
}
__global__ void k_scatter(const int* __restrict__ ei, int* __restrict__ cur, int* __restrict__ csr){
    int e = blockIdx.x*blockDim.x + threadIdx.x;
    if (e < E_EDGES){
        int d = ei[E_EDGES + e];
        int p = atomicAdd(&cur[d], 1);
        csr[p] = ei[e];
    }
}

// ---------- GAT1 apply: softmax + bf16 gather SpMM + head-mean + lin1 + sigmoid ----------
// R12: one WAVE per dst, 4 dst/block (grid 5000). Old: 4 waves co-process 1 dst with
// 3 barriers; score phase used ~33/256 threads; gather chains were 8 iters/wave.
// New: scores in regs (slots lane, lane+64; cap 128 >> max deg ~70), softmax via
// shfl_xor only, normalized weights -> per-wave LDS slab, ONE barrier, full ~33-iter
// gather/wave (1-deep prefetch, same coalesced uint2 row loads as R5), head-mean via
// shfl_xor(16/32). fp32 reassociation only vs old version.
__global__ __launch_bounds__(256)
void k_gat1(const unsigned short* __restrict__ hcb, const float* __restrict__ hlin,
            const float* __restrict__ es, const float* __restrict__ ed,
            const int* __restrict__ offs, const int* __restrict__ csr,
            const float* __restrict__ bc1, const float* __restrict__ bl1,
            float* __restrict__ h1)
{
    int t = threadIdx.x;
    int lane = t & 63, wv = t >> 6;
    int d = blockIdx.x * 4 + wv;            // grid 5000, exact
    __shared__ float4 wcache[4][MAXN];      // normalized per-head weights
    __shared__ int    wsrc[4][MAXN];
    int o = offs[d];
    int deg = offs[d+1] - o;
    int total = deg + 1;                    // + self loop
    if (total > MAXN) total = MAXN;
    float4 edv = *(const float4*)(ed + d*4);

    // ---- scores: slot0 = lane, slot1 = lane+64 ----
    float s0x=-1e30f, s0y=-1e30f, s0z=-1e30f, s0w=-1e30f;
    float s1x=-1e30f, s1y=-1e30f, s1z=-1e30f, s1w=-1e30f;
    if (lane < total){
        int s = (lane < deg) ? csr[o + lane] : d;
        wsrc[wv][lane] = s;
        float4 ev = *(const float4*)(es + s*4);
        s0x = leakyf_(ev.x + edv.x); s0y = leakyf_(ev.y + edv.y);
        s0z = leakyf_(ev.z + edv.z); s0w = leakyf_(ev.w + edv.w);
    }
    int i1 = lane + 64;
    if (i1 < total){
        int s = (i1 < deg) ? csr[o + i1] : d;
        wsrc[wv][i1] = s;
        float4 ev = *(const float4*)(es + s*4);
        s1x = leakyf_(ev.x + edv.x); s1y = leakyf_(ev.y + edv.y);
        s1z = leakyf_(ev.z + edv.z); s1w = leakyf_(ev.w + edv.w);
    }
    // ---- per-head max over both slots, then wave ----
    float m0 = fmaxf(s0x, s1x), m1 = fmaxf(s0y, s1y);
    float m2 = fmaxf(s0z, s1z), m3 = fmaxf(s0w, s1w);
    #pragma unroll
    for (int m = 32; m; m >>= 1){
        m0 = fmaxf(m0, __shfl_xor(m0, m)); m1 = fmaxf(m1, __shfl_xor(m1, m));
        m2 = fmaxf(m2, __shfl_xor(m2, m)); m3 = fmaxf(m3, __shfl_xor(m3, m));
    }
    // ---- exp (inactive slots: exp(-1e30 - m) -> 0) ----
    float e0x = __expf(s0x - m0), e0y = __expf(s0y - m1);
    float e0z = __expf(s0z - m2), e0w = __expf(s0w - m3);
    float e1x = __expf(s1x - m0), e1y = __expf(s1y - m1);
    float e1z = __expf(s1z - m2), e1w = __expf(s1w - m3);
    float q0 = e0x + e1x, q1 = e0y + e1y, q2 = e0z + e1z, q3 = e0w + e1w;
    #pragma unroll
    for (int m = 32; m; m >>= 1){
        q0 += __shfl_xor(q0, m); q1 += __shfl_xor(q1, m);
        q2 += __shfl_xor(q2, m); q3 += __shfl_xor(q3, m);
    }
    float inv0 = 1.0f/q0, inv1 = 1.0f/q1, inv2 = 1.0f/q2, inv3 = 1.0f/q3;
    if (lane < total) wcache[wv][lane] = make_float4(e0x*inv0, e0y*inv1, e0z*inv2, e0w*inv3);
    if (i1   < total) wcache[wv][i1]   = make_float4(e1x*inv0, e1y*inv1, e1z*inv2, e1w*inv3);
    __syncthreads();     // one barrier: LDS weights visible to own wave's gather

    // ---- gather: lane owns flat cols 4u..4u+3 (head u>>4); full loop per wave ----
    int u = lane;
    int h = u >> 4;
    float a0=0.f, a1=0.f, a2=0.f, a3=0.f;
    uint2 v; float al;
    {
        int s = wsrc[wv][0];
        al = ((const float*)&wcache[wv][0])[h];
        v = *(const uint2*)(hcb + (size_t)s*256 + u*4);
    }
    for (int idx = 0; idx < total; ){
        uint2 vc = v; float ac = al;
        int nx = idx + 1;
        if (nx < total){                 // wave-uniform
            int s2 = wsrc[wv][nx];
            al = ((const float*)&wcache[wv][nx])[h];
            v = *(const uint2*)(hcb + (size_t)s2*256 + u*4);
        }
        a0 += ac * __uint_as_float(vc.x << 16);
        a1 += ac * __uint_as_float(vc.x & 0xFFFF0000u);
        a2 += ac * __uint_as_float(vc.y << 16);
        a3 += ac * __uint_as_float(vc.y & 0xFFFF0000u);
        idx = nx;
    }
    // ---- head-mean: sum over lanes differing in bits 4,5 (same within-col, slot) ----
    a0 += __shfl_xor(a0, 16); a1 += __shfl_xor(a1, 16);
    a2 += __shfl_xor(a2, 16); a3 += __shfl_xor(a3, 16);
    a0 += __shfl_xor(a0, 32); a1 += __shfl_xor(a1, 32);
    a2 += __shfl_xor(a2, 32); a3 += __shfl_xor(a3, 32);
    if (lane < 16){
        int cb = lane * 4;               // within-head col base
        float4 hl  = *(const float4*)(hlin + (size_t)d*64 + cb);
        float4 bcv = *(const float4*)(bc1 + cb);
        float4 blv = *(const float4*)(bl1 + cb);
        float4 outv;
        outv.x = sigmoidf_(0.25f*a0 + bcv.x + hl.x + blv.x);
        outv.y = sigmoidf_(0.25f*a1 + bcv.y + hl.y + blv.y);
        outv.z = sigmoidf_(0.25f*a2 + bcv.z + hl.z + blv.z);
        outv.w = sigmoidf_(0.25f*a3 + bcv.w + hl.w + blv.w);
        *(float4*)(h1 + (size_t)d*64 + cb) = outv;
    }
}

// ---------- conv2 prep ----------
__global__ void k_conv2prep(const float* __restrict__ h1, const float* __restrict__ W2c,
                            const float* __restrict__ as2, const float* __restrict__ ad2,
                            const float* __restrict__ Wl2, float* __restrict__ hh2,
                            float* __restrict__ es2, float* __restrict__ ed2,
                            float* __restrict__ lv)
{
    int i = blockIdx.x; int k = threadIdx.x; // 64
    float hv = h1[i*64 + k];
    #pragma unroll
    for (int j = 0; j < 4; ++j){
        float v = hv * W2c[k*4 + j];
        for (int m = 32; m; m >>= 1) v += __shfl_xor(v, m);
        if (k == 0){ hh2[i*4+j] = v; es2[i*4+j] = v*as2[j]; ed2[i*4+j] = v*ad2[j]; }
    }
    float v = hv * Wl2[k];
    for (int m = 32; m; m >>= 1) v += __shfl_xor(v, m);
    if (k == 0) lv[i] = v;
}

// ---------- GAT2 apply ----------
__global__ void k_gat2(const float* __restrict__ hh2, const float* __restrict__ es2,
                       const float* __restrict__ ed2, const int* __restrict__ offs,
                       const int* __restrict__ csr, const float* __restrict__ lv,
                       const float* __restrict__ bc2, const float* __restrict__ bl2,
                       float* __restrict__ feat)
{
    int d = blockIdx.x; int j = threadIdx.x; // 64
    int o = offs[d];
    int deg = offs[d+1] - o;
    int total = deg + 1;
    float edst[4];
    #pragma unroll
    for (int h = 0; h < 4; ++h) edst[h] = ed2[d*4+h];
    float lmax[4] = {-1e30f,-1e30f,-1e30f,-1e30f};
    for (int idx = j; idx < total; idx += 64){
        int s = (idx < deg) ? csr[o + idx] : d;
        #pragma unroll
        for (int h = 0; h < 4; ++h)
            lmax[h] = fmaxf(lmax[h], leakyf_(es2[s*4+h] + edst[h]));
    }
    #pragma unroll
    for (int h = 0; h < 4; ++h)
        for (int m = 32; m; m >>= 1) lmax[h] = fmaxf(lmax[h], __shfl_xor(lmax[h], m));
    float lsum[4] = {0.f,0.f,0.f,0.f};
    float lnum[4] = {0.f,0.f,0.f,0.f};
    for (int idx = j; idx < total; idx += 64){
        int s = (idx < deg) ? csr[o + idx] : d;
        #pragma unroll
        for (int h = 0; h < 4; ++h){
            float e  = leakyf_(es2[s*4+h] + edst[h]);
            float ex = __expf(e - lmax[h]);
            lsum[h] += ex;
            lnum[h] += ex * hh2[s*4+h];
        }
    }
    #pragma unroll
    for (int h = 0; h < 4; ++h){
        for (int m = 32; m; m >>= 1){ lsum[h] += __shfl_xor(lsum[h], m); lnum[h] += __shfl_xor(lnum[h], m); }
    }
    if (j == 0){
        float sum = 0.f;
        #pragma unroll
        for (int h = 0; h < 4; ++h) sum += lnum[h] / lsum[h];
        feat[d] = sigmoidf_(0.25f*sum + bc2[0] + lv[d] + bl2[0]);
    }
}

// ---------- prep A1 (bf16, [row][k], row-major = ctrl's layout, no transpose) ----------
__global__ void k_prepA(const float* __restrict__ ctrl, const float* __restrict__ feat,
                        unsigned short* __restrict__ Abf)
{
    int col = blockIdx.x*256 + threadIdx.x;
    int row = blockIdx.y;
    if (col < 20000)
        Abf[(size_t)row*KA1 + col] = f2bf(ctrl[(size_t)row*20000 + col] + feat[col]);
}

// ---------- pert MLP -> writes Abf1 cols 20000..20063 (+ zero pad to 20095) ----------
__global__ void k_pert(const float* __restrict__ pert, const float* __restrict__ W1,
                       const float* __restrict__ b1, const float* __restrict__ W2,
                       const float* __restrict__ b2, unsigned short* __restrict__ Abf)
{
    int r = blockIdx.x; int t = threadIdx.x; // 128
    __shared__ float hid[128];
    float acc = 0.f;
    for (int k = 0; k < PD; ++k) acc += pert[r*PD + k] * W1[k*128 + t];
    hid[t] = sigmoidf_(acc + b1[t]);
    __syncthreads();
    if (t < 64){
        float a2 = 0.f;
        for (int k = 0; k < 128; ++k) a2 += hid[k] * W2[k*64 + t];
        Abf[(size_t)r*KA1 + 20000 + t] = f2bf(a2 + b2[t]);
    } else if (t < 96){
        Abf[(size_t)r*KA1 + 20000 + t] = 0;  // zero K-pad 20064..20095
    }
}

// ---------- pred GEMM1 (MFMA bf16): part[ks] = A[128 x Kchunk] @ W1 ----------
__global__ __launch_bounds__(256, 2)
void k_gemm1m(const unsigned short* __restrict__ Abf, const float* __restrict__ W1,
              float* __restrict__ part)
{
    int t = threadIdx.x;
    int lane = t & 63, wv = t >> 6;
    int lane16 = lane & 15, quad = lane >> 4, quad8 = quad * 8;
    int colbase = blockIdx.x * 64;
    int ks = blockIdx.y;
    int sbeg = (ks * NSTEP1) / KSPLIT1;
    int send = ((ks + 1) * NSTEP1) / KSPLIT1;
    int nsteps = send - sbeg;
    int kbeg = sbeg * 32;
    __shared__ unsigned short Bs[2][32*64];

    v4f acc[8];
    #pragma unroll
    for (int i = 0; i < 8; ++i) acc[i] = (v4f){0.f,0.f,0.f,0.f};

    int krow = t >> 3;           // 0..31
    int ng   = (t & 7) * 8;      // 0..56
    {
        int kg = kbeg + krow;
        short8 p;
        if (kg < 20064){
            float4 a = *(const float4*)(W1 + (size_t)kg*1024 + colbase + ng);
            float4 b = *(const float4*)(W1 + (size_t)kg*1024 + colbase + ng + 4);
            p[0]=(short)f2bf(a.x); p[1]=(short)f2bf(a.y); p[2]=(short)f2bf(a.z); p[3]=(short)f2bf(a.w);
            p[4]=(short)f2bf(b.x); p[5]=(short)f2bf(b.y); p[6]=(short)f2bf(b.z); p[7]=(short)f2bf(b.w);
        } else {
            p = (short8){0,0,0,0,0,0,0,0};
        }
        *(short8*)&Bs[0][krow*64 + ng] = p;
    }
    __syncthreads();

    int cur = 0;
    for (int s = 0; s < nsteps; ++s){
        int kg = kbeg + s*32;
        short8 bfrag;
        #pragma unroll
        for (int j = 0; j < 8; ++j)
            bfrag[j] = (short)Bs[cur][(quad8 + j)*64 + wv*16 + lane16];
        float w[8];
        bool more = (s + 1) < nsteps;
        if (more){
            int kn = kg + 32 + krow;
            if (kn < 20064){
                float4 a = *(const float4*)(W1 + (size_t)kn*1024 + colbase + ng);
                float4 b = *(const float4*)(W1 + (size_t)kn*1024 + colbase + ng + 4);
                w[0]=a.x; w[1]=a.y; w[2]=a.z; w[3]=a.w; w[4]=b.x; w[5]=b.y; w[6]=b.z; w[7]=b.w;
            } else {
                #pragma unroll
                for (int i = 0; i < 8; ++i) w[i] = 0.f;
            }
        }
        #pragma unroll
        for (int mt = 0; mt < 8; ++mt){
            short8 af = *(const short8*)(Abf + (size_t)(mt*16 + lane16)*KA1 + kg + quad8);
            acc[mt] = __builtin_amdgcn_mfma_f32_16x16x32_bf16(af, bfrag, acc[mt], 0, 0, 0);
        }
        if (more){
            short8 p;
            #pragma unroll
            for (int i = 0; i < 8; ++i) p[i] = (short)f2bf(w[i]);
            *(short8*)&Bs[cur^1][krow*64 + ng] = p;
        }
        __syncthreads();
        cur ^= 1;
    }
    float* dst = part + (size_t)ks * 131072;
    int col = colbase + wv*16 + lane16;
    #pragma unroll
    for (int mt = 0; mt < 8; ++mt)
        #pragma unroll
        for (int r = 0; r < 4; ++r)
            dst[(size_t)(mt*16 + quad*4 + r)*1024 + col] = acc[mt][r];
}

// ---------- reduce partials + bias + sigmoid -> hidbf[128][1024] bf16 ----------
__global__ void k_reduce(const float* __restrict__ part, const float* __restrict__ b1,
                         unsigned short* __restrict__ hidbf)
{
    int row = blockIdx.x;                       // 0..127
    int col = blockIdx.y*256 + threadIdx.x;     // 0..1023
    float s = 0.f;
    #pragma unroll
    for (int ks = 0; ks < KSPLIT1; ++ks)
        s += part[(size_t)ks*131072 + (size_t)row*1024 + col];
    hidbf[(size_t)row*1024 + col] = f2bf(sigmoidf_(s + b1[col]));
}

// ---------- pred GEMM2 (MFMA bf16): out = hid[128x1024] @ W2 + b2 ----------
__global__ __launch_bounds__(256, 2)
void k_gemm2m(const unsigned short* __restrict__ hidbf, const float* __restrict__ W2,
              const float* __restrict__ b2, float* __restrict__ out)
{
    int t = threadIdx.x;
    int lane = t & 63, wv = t >> 6;
    int lane16 = lane & 15, quad = lane >> 4, quad8 = quad * 8;
    int colbase = blockIdx.x * 64;
    int rbase   = blockIdx.y * 64;
    __shared__ unsigned short Bs[2][32*64];

    v4f acc[4];
    #pragma unroll
    for (int i = 0; i < 4; ++i) acc[i] = (v4f){0.f,0.f,0.f,0.f};

    int krow = t >> 3;
    int ng   = (t & 7) * 8;
    bool cv = (colbase + ng) < 20000;   // 8-col granule, 20000 % 8 == 0
    {
        short8 p = (short8){0,0,0,0,0,0,0,0};
        if (cv){
            float4 a = *(const float4*)(W2 + (size_t)krow*20000 + colbase + ng);
            float4 b = *(const float4*)(W2 + (size_t)krow*20000 + colbase + ng + 4);
            p[0]=(short)f2bf(a.x); p[1]=(short)f2bf(a.y); p[2]=(short)f2bf(a.z); p[3]=(short)f2bf(a.w);
            p[4]=(short)f2bf(b.x); p[5]=(short)f2bf(b.y); p[6]=(short)f2bf(b.z); p[7]=(short)f2bf(b.w);
        }
        *(short8*)&Bs[0][krow*64 + ng] = p;
    }
    __syncthreads();

    int cur = 0;
    for (int s = 0; s < 32; ++s){
        int kg = s*32;
        short8 bfrag;
        #pragma unroll
        for (int j = 0; j < 8; ++j)
            bfrag[j] = (short)Bs[cur][(quad8 + j)*64 + wv*16 + lane16];
        float w[8];
        bool more = s < 31;
        if (more){
            if (cv){
                int kn = kg + 32 + krow;
                float4 a = *(const float4*)(W2 + (size_t)kn*20000 + colbase + ng);
                float4 b = *(const float4*)(W2 + (size_t)kn*20000 + colbase + ng + 4);
                w[0]=a.x; w[1]=a.y; w[2]=a.z; w[3]=a.w; w[4]=b.x; w[5]=b.y; w[6]=b.z; w[7]=b.w;
            } else {
                #pragma unroll
                for (int i = 0; i < 8; ++i) w[i] = 0.f;
            }
        }
        #pragma unroll
        for (int mt = 0; mt < 4; ++mt){
            short8 af = *(const short8*)(hidbf + (size_t)(rbase + mt*16 + lane16)*KA2 + kg + quad8);
            acc[mt] = __builtin_amdgcn_mfma_f32_16x16x32_bf16(af, bfrag, acc[mt], 0, 0, 0);
        }
        if (more){
            short8 p;
            #pragma unroll
            for (int i = 0; i < 8; ++i) p[i] = (short)f2bf(w[i]);
            *(short8*)&Bs[cur^1][krow*64 + ng] = p;
        }
        __syncthreads();
        cur ^= 1;
    }
    int col = colbase + wv*16 + lane16;
    if (col < 20000){
        float bb = b2[col];
        #pragma unroll
        for (int mt = 0; mt < 4; ++mt)
            #pragma unroll
            for (int r = 0; r < 4; ++r)
                out[(size_t)(rbase + mt*16 + quad*4 + r)*20000 + col] = acc[mt][r] + bb;
    }
}

extern "C" void kernel_launch(void* const* d_in, const int* in_sizes, int n_in,
                              void* d_out, int out_size, void* d_ws, size_t ws_size,
                              hipStream_t stream)
{
    const float* x    = (const float*)d_in[0];
    const int*   ei   = (const int*)  d_in[1];
    const int*   pos  = (const int*)  d_in[2];
    const float* ctrl = (const float*)d_in[3];
    const float* pert = (const float*)d_in[4];
    const float* ge   = (const float*)d_in[5];
    const float* c1W  = (const float*)d_in[6];
    const float* c1as = (const float*)d_in[7];
    const float* c1ad = (const float*)d_in[8];
    const float* c1b  = (const float*)d_in[9];
    const float* l1W  = (const float*)d_in[10];
    const float* l1b  = (const float*)d_in[11];
    const float* c2W  = (const float*)d_in[12];
    const float* c2as = (const float*)d_in[13];
    const float* c2ad = (const float*)d_in[14];
    const float* c2b  = (const float*)d_in[15];
    const float* l2W  = (const float*)d_in[16];
    const float* l2b  = (const float*)d_in[17];
    const float* pW1  = (const float*)d_in[18];
    const float* pb1  = (const float*)d_in[19];
    const float* pW2  = (const float*)d_in[20];
    const float* pb2  = (const float*)d_in[21];
    const float* prW1 = (const float*)d_in[22];
    const float* prb1 = (const float*)d_in[23];
    const float* prW2 = (const float*)d_in[24];
    const float* prb2 = (const float*)d_in[25];
    float* out = (float*)d_out;

    char* ws = (char*)d_ws;
    size_t off = 0;
    auto alloc = [&](size_t bytes)->void*{
        void* pp = ws + off;
        off += (bytes + 255) & ~(size_t)255;
        return pp;
    };
    unsigned short* hcb  = (unsigned short*)alloc((size_t)G*256*2);  // 10.24 MB
    float* hlin = (float*)alloc((size_t)G*64*4);                      // 5.12 MB
    float* h1   = (float*)alloc((size_t)G*64*4);
    float* es1  = (float*)alloc((size_t)G*4*4);
    float* ed1  = (float*)alloc((size_t)G*4*4);
    float* hh2  = (float*)alloc((size_t)G*4*4);
    float* es2  = (float*)alloc((size_t)G*4*4);
    float* ed2  = (float*)alloc((size_t)G*4*4);
    float* lv   = (float*)alloc((size_t)G*4);
    float* feat = (float*)alloc((size_t)G*4);
    unsigned short* hidbf = (unsigned short*)alloc((size_t)128*KA2*2);
    unsigned short* Abf1  = (unsigned short*)alloc((size_t)128*KA1*2);   // 5.1 MB
    float* part = (float*)alloc((size_t)KSPLIT1*131072*4);               // 16.8 MB
    int*   cnt  = (int*)alloc((size_t)G*4);
    int*   offs = (int*)alloc((size_t)(G+1)*4);
    int*   cur  = (int*)alloc((size_t)G*4);
    int*   csr  = (int*)alloc((size_t)E_EDGES*4);

    hipMemsetAsync(cnt, 0, (size_t)G*4, stream);

    k_hist   <<<(E_EDGES+255)/256, 256, 0, stream>>>(ei, cnt);
    k_scan   <<<1, 1024, 0, stream>>>(cnt, offs, cur);
    k_scatter<<<(E_EDGES+255)/256, 256, 0, stream>>>(ei, cur, csr);

    k_hc       <<<(G + ROWS_HC - 1)/ROWS_HC, 320, 0, stream>>>(x, pos, ge, c1W, l1W, c1as, c1ad,
                                         hcb, hlin, es1, ed1);
    k_gat1     <<<G/4, 256, 0, stream>>>(hcb, hlin, es1, ed1, offs, csr, c1b, l1b, h1);
    k_conv2prep<<<G, 64, 0, stream>>>(h1, c2W, c2as, c2ad, l2W, hh2, es2, ed2, lv);
    k_gat2     <<<G, 64, 0, stream>>>(hh2, es2, ed2, offs, csr, lv, c2b, l2b, feat);

    dim3 gp(79, 128);
    k_prepA<<<gp, 256, 0, stream>>>(ctrl, feat, Abf1);
    k_pert <<<BATCH, 128, 0, stream>>>(pert, pW1, pb1, pW2, pb2, Abf1);

    dim3 g1(16, KSPLIT1);
    k_gemm1m<<<g1, 256, 0, stream>>>(Abf1, prW1, part);
    dim3 gr(128, 4);
    k_reduce<<<gr, 256, 0, stream>>>(part, prb1, hidbf);
    dim3 g2(313, 2);
    k_gemm2m<<<g2, 256, 0, stream>>>(hidbf, prW2, prb2, out);
}

// Round 15
// 595.167 us; speedup vs baseline: 1.1068x; 1.0176x over previous
//
#include <hip/hip_runtime.h>
#include <math.h>

#define G 20000
#define E_EDGES 640000
#define HID 64
#define NHEAD 4
#define BATCH 128
#define PD 600
#define NEG 0.2f
#define MAXN 128           // per-dst neighbor cap (deg ~ Poisson(32), max ~70)

#define KA1 20096          // 20064 padded to multiple of 32
#define NSTEP1 628         // 20096 / 32
#define KSPLIT1 32
#define KA2 1024

#define ROWS_HC 16         // rows per k_hc block: 1250 blocks (R5-verified config)

typedef float v4f __attribute__((ext_vector_type(4)));
typedef short short8 __attribute__((ext_vector_type(8)));

__device__ __forceinline__ float sigmoidf_(float x){ return 1.0f/(1.0f+__expf(-x)); }
__device__ __forceinline__ float leakyf_(float x){ return x>=0.f ? x : NEG*x; }
__device__ __forceinline__ unsigned short f2bf(float f){
    unsigned int u = __float_as_uint(f);
    return (unsigned short)((u + 0x7FFFu + ((u >> 16) & 1u)) >> 16);
}
__device__ __forceinline__ float bf2f(unsigned short b){
    return __uint_as_float(((unsigned int)b) << 16);
}

// ---------- Stage 1 fused: hc/es/ed.  ROWS_HC rows/block, 320 threads. ----------
// R14: 4 independent accumulators (chain 64 -> ~16 steps; fp32 reassoc only).
// R12 evidence: both LDS (82us) and scalar (122us) variants latency-bound,
// VALUBusy 26% with single-acc chain. Structure otherwise R5-verified.
__global__ __launch_bounds__(320)
void k_hc(const float* __restrict__ x, const int* __restrict__ pos,
          const float* __restrict__ ge, const float* __restrict__ Wc,
          const float* __restrict__ Wl, const float* __restrict__ as_,
          const float* __restrict__ ad_,
          unsigned short* __restrict__ hcb, float* __restrict__ hlin,
          float* __restrict__ es, float* __restrict__ ed)
{
    int t = threadIdx.x;                 // 320
    int rb = blockIdx.x * ROWS_HC;       // grid 1250
    __shared__ float xc[ROWS_HC][68];    // row stride 272B (16B aligned)
    for (int l = t; l < ROWS_HC*65; l += 320){
        int r = l / 65, k = l - r*65;
        int row = rb + r;
        float v = 0.f;
        if (row < G) v = (k == 0) ? x[row] : ge[pos[row]*HID + (k-1)];
        xc[r][k] = v;
    }
    float wcol[65];
    if (t < 256){
        #pragma unroll
        for (int k = 0; k < 65; ++k) wcol[k] = Wc[k*256 + t];
    } else {
        int c = t - 256;
        #pragma unroll
        for (int k = 0; k < 65; ++k) wcol[k] = Wl[k*64 + c];
    }
    float a_s = 0.f, a_d = 0.f;
    if (t < 256){ a_s = as_[t]; a_d = ad_[t]; }
    __syncthreads();

    int nrow = G - rb; if (nrow > ROWS_HC) nrow = ROWS_HC;
    for (int r = 0; r < nrow; ++r){
        int row = rb + r;
        const float4* xr = (const float4*)&xc[r][0];
        float b0 = 0.f, b1 = 0.f, b2 = 0.f, b3 = 0.f;
        #pragma unroll
        for (int k4 = 0; k4 < 16; ++k4){
            float4 v = xr[k4];
            b0 += v.x*wcol[4*k4];
            b1 += v.y*wcol[4*k4+1];
            b2 += v.z*wcol[4*k4+2];
            b3 += v.w*wcol[4*k4+3];
        }
        float acc = (b0 + b1) + (b2 + b3) + xc[r][64] * wcol[64];
        if (t < 256){
            hcb[(size_t)row*256 + t] = f2bf(acc);
            float v1 = acc * a_s, v2 = acc * a_d;
            #pragma unroll
            for (int m = 32; m; m >>= 1){ v1 += __shfl_xor(v1, m); v2 += __shfl_xor(v2, m); }
            if ((t & 63) == 0){ int h = t >> 6; es[row*4+h] = v1; ed[row*4+h] = v2; }
        } else {
            hlin[(size_t)row*64 + (t - 256)] = acc;
        }
    }
}

// ---------- CSR build ----------
__global__ void k_hist(const int* __restrict__ ei, int* __restrict__ cnt){
    int e = blockIdx.x*blockDim.x + threadIdx.x;
    if (e < E_EDGES) atomicAdd(&cnt[ei[E_EDGES + e]], 1);
}
__global__ void k_scan(const int* __restrict__ cnt, int* __restrict__ offs,
                       int* __restrict__ cur)
{
    __shared__ int ts[1024];
    int t = threadIdx.x;
    int base = t * 20;
    int loc[20];
    int s = 0;
    #pragma unroll
    for (int j = 0; j < 20; ++j){
        int i = base + j;
        int v = (i < G) ? cnt[i] : 0;
        loc[j] = s; s += v;
    }
    ts[t] = s;
    __syncthreads();
    for (int off = 1; off < 1024; off <<= 1){
        int add = (t >= off) ? ts[t - off] : 0;
        __syncthreads();
        ts[t] += add;
        __syncthreads();
    }
    int tb = (t == 0) ? 0 : ts[t - 1];
    #pragma unroll
    for (int j = 0; j < 20; ++j){
        int i = base + j;
        if (i < G){ int o = tb + loc[j]; offs[i] = o; cur[i] = o; }
    }
    if (t == 0) offs[G] = ts[1023];
}
__global__ void k_scatter(const int* __restrict__ ei, int* __restrict__ cur, int* __restrict__ csr){
    int e = blockIdx.x*blockDim.x + threadIdx.x;
    if (e < E_EDGES){
        int d = ei[E_EDGES + e];
        int p = atomicAdd(&cur[d], 1);
        csr[p] = ei[e];
    }
}

// ---------- GAT1 apply + FUSED conv2prep ----------
// R12 (verified R14): one WAVE per dst, 4 dst/block, one barrier, shfl softmax.
// R14: conv2prep fused into epilogue. h1 was consumed ONLY by conv2prep, so h1 is
// never materialized: after head-mean shfl(16/32) ALL lanes hold the 4-col sums for
// cols 4*(lane&15)..+3; apply sigmoid in-register, compute conv2/lin2 partials
// (20 FMA, L2-cached weights), shfl_xor(1,2,4,8) exact-reduce, lane 0 writes
// hh2/es2/ed2/lv. Saves one 20000-block dispatch + 10MB h1 traffic. fp32 reassoc only.
__global__ __launch_bounds__(256)
void k_gat1(const unsigned short* __restrict__ hcb, const float* __restrict__ hlin,
            const float* __restrict__ es, const float* __restrict__ ed,
            const int* __restrict__ offs, const int* __restrict__ csr,
            const float* __restrict__ bc1, const float* __restrict__ bl1,
            const float* __restrict__ W2c, const float* __restrict__ as2,
            const float* __restrict__ ad2, const float* __restrict__ Wl2,
            float* __restrict__ hh2, float* __restrict__ es2o,
            float* __restrict__ ed2o, float* __restrict__ lv)
{
    int t = threadIdx.x;
    int lane = t & 63, wv = t >> 6;
    int d = blockIdx.x * 4 + wv;            // grid 5000, exact
    __shared__ float4 wcache[4][MAXN];      // normalized per-head weights
    __shared__ int    wsrc[4][MAXN];
    int o = offs[d];
    int deg = offs[d+1] - o;
    int total = deg + 1;                    // + self loop
    if (total > MAXN) total = MAXN;
    float4 edv = *(const float4*)(ed + d*4);

    // ---- scores: slot0 = lane, slot1 = lane+64 ----
    float s0x=-1e30f, s0y=-1e30f, s0z=-1e30f, s0w=-1e30f;
    float s1x=-1e30f, s1y=-1e30f, s1z=-1e30f, s1w=-1e30f;
    if (lane < total){
        int s = (lane < deg) ? csr[o + lane] : d;
        wsrc[wv][lane] = s;
        float4 ev = *(const float4*)(es + s*4);
        s0x = leakyf_(ev.x + edv.x); s0y = leakyf_(ev.y + edv.y);
        s0z = leakyf_(ev.z + edv.z); s0w = leakyf_(ev.w + edv.w);
    }
    int i1 = lane + 64;
    if (i1 < total){
        int s = (i1 < deg) ? csr[o + i1] : d;
        wsrc[wv][i1] = s;
        float4 ev = *(const float4*)(es + s*4);
        s1x = leakyf_(ev.x + edv.x); s1y = leakyf_(ev.y + edv.y);
        s1z = leakyf_(ev.z + edv.z); s1w = leakyf_(ev.w + edv.w);
    }
    // ---- per-head max over both slots, then wave ----
    float m0 = fmaxf(s0x, s1x), m1 = fmaxf(s0y, s1y);
    float m2 = fmaxf(s0z, s1z), m3 = fmaxf(s0w, s1w);
    #pragma unroll
    for (int m = 32; m; m >>= 1){
        m0 = fmaxf(m0, __shfl_xor(m0, m)); m1 = fmaxf(m1, __shfl_xor(m1, m));
        m2 = fmaxf(m2, __shfl_xor(m2, m)); m3 = fmaxf(m3, __shfl_xor(m3, m));
    }
    // ---- exp (inactive slots -> 0) ----
    float e0x = __expf(s0x - m0), e0y = __expf(s0y - m1);
    float e0z = __expf(s0z - m2), e0w = __expf(s0w - m3);
    float e1x = __expf(s1x - m0), e1y = __expf(s1y - m1);
    float e1z = __expf(s1z - m2), e1w = __expf(s1w - m3);
    float q0 = e0x + e1x, q1 = e0y + e1y, q2 = e0z + e1z, q3 = e0w + e1w;
    #pragma unroll
    for (int m = 32; m; m >>= 1){
        q0 += __shfl_xor(q0, m); q1 += __shfl_xor(q1, m);
        q2 += __shfl_xor(q2, m); q3 += __shfl_xor(q3, m);
    }
    float inv0 = 1.0f/q0, inv1 = 1.0f/q1, inv2 = 1.0f/q2, inv3 = 1.0f/q3;
    if (lane < total) wcache[wv][lane] = make_float4(e0x*inv0, e0y*inv1, e0z*inv2, e0w*inv3);
    if (i1   < total) wcache[wv][i1]   = make_float4(e1x*inv0, e1y*inv1, e1z*inv2, e1w*inv3);
    __syncthreads();     // one barrier

    // ---- gather: lane owns flat cols 4u..4u+3 (head u>>4) ----
    int u = lane;
    int h = u >> 4;
    float a0=0.f, a1=0.f, a2=0.f, a3=0.f;
    uint2 v; float al;
    {
        int s = wsrc[wv][0];
        al = ((const float*)&wcache[wv][0])[h];
        v = *(const uint2*)(hcb + (size_t)s*256 + u*4);
    }
    for (int idx = 0; idx < total; ){
        uint2 vc = v; float ac = al;
        int nx = idx + 1;
        if (nx < total){                 // wave-uniform
            int s2 = wsrc[wv][nx];
            al = ((const float*)&wcache[wv][nx])[h];
            v = *(const uint2*)(hcb + (size_t)s2*256 + u*4);
        }
        a0 += ac * __uint_as_float(vc.x << 16);
        a1 += ac * __uint_as_float(vc.x & 0xFFFF0000u);
        a2 += ac * __uint_as_float(vc.y << 16);
        a3 += ac * __uint_as_float(vc.y & 0xFFFF0000u);
        idx = nx;
    }
    // ---- head-mean: after these, ALL lanes hold sums for cols 4*(lane&15)..+3 ----
    a0 += __shfl_xor(a0, 16); a1 += __shfl_xor(a1, 16);
    a2 += __shfl_xor(a2, 16); a3 += __shfl_xor(a3, 16);
    a0 += __shfl_xor(a0, 32); a1 += __shfl_xor(a1, 32);
    a2 += __shfl_xor(a2, 32); a3 += __shfl_xor(a3, 32);

    // ---- fused epilogue: h1 in-register, conv2prep reductions ----
    int cb = (lane & 15) * 4;            // this lane's col base (dup x4 across wave)
    float4 hl  = *(const float4*)(hlin + (size_t)d*64 + cb);
    float4 bcv = *(const float4*)(bc1 + cb);
    float4 blv = *(const float4*)(bl1 + cb);
    float h0 = sigmoidf_(0.25f*a0 + bcv.x + hl.x + blv.x);
    float h1v= sigmoidf_(0.25f*a1 + bcv.y + hl.y + blv.y);
    float h2v= sigmoidf_(0.25f*a2 + bcv.z + hl.z + blv.z);
    float h3v= sigmoidf_(0.25f*a3 + bcv.w + hl.w + blv.w);
    // conv2 partials over this lane's 4 cols, for each head j
    float p0 = h0*W2c[cb*4+0] + h1v*W2c[(cb+1)*4+0] + h2v*W2c[(cb+2)*4+0] + h3v*W2c[(cb+3)*4+0];
    float p1 = h0*W2c[cb*4+1] + h1v*W2c[(cb+1)*4+1] + h2v*W2c[(cb+2)*4+1] + h3v*W2c[(cb+3)*4+1];
    float p2 = h0*W2c[cb*4+2] + h1v*W2c[(cb+1)*4+2] + h2v*W2c[(cb+2)*4+2] + h3v*W2c[(cb+3)*4+2];
    float p3 = h0*W2c[cb*4+3] + h1v*W2c[(cb+1)*4+3] + h2v*W2c[(cb+2)*4+3] + h3v*W2c[(cb+3)*4+3];
    float pl = h0*Wl2[cb] + h1v*Wl2[cb+1] + h2v*Wl2[cb+2] + h3v*Wl2[cb+3];
    // exact reduce over the 16 distinct col-groups (lanes 16+ hold duplicates,
    // reduced independently within their own group of 16 -> same totals)
    #pragma unroll
    for (int m = 1; m <= 8; m <<= 1){
        p0 += __shfl_xor(p0, m); p1 += __shfl_xor(p1, m);
        p2 += __shfl_xor(p2, m); p3 += __shfl_xor(p3, m);
        pl += __shfl_xor(pl, m);
    }
    if (lane == 0){
        hh2[d*4+0] = p0; hh2[d*4+1] = p1; hh2[d*4+2] = p2; hh2[d*4+3] = p3;
        es2o[d*4+0] = p0*as2[0]; es2o[d*4+1] = p1*as2[1];
        es2o[d*4+2] = p2*as2[2]; es2o[d*4+3] = p3*as2[3];
        ed2o[d*4+0] = p0*ad2[0]; ed2o[d*4+1] = p1*ad2[1];
        ed2o[d*4+2] = p2*ad2[2]; ed2o[d*4+3] = p3*ad2[3];
        lv[d] = pl;
    }
}

// ---------- GAT2 apply ----------
__global__ void k_gat2(const float* __restrict__ hh2, const float* __restrict__ es2,
                       const float* __restrict__ ed2, const int* __restrict__ offs,
                       const int* __restrict__ csr, const float* __restrict__ lv,
                       const float* __restrict__ bc2, const float* __restrict__ bl2,
                       float* __restrict__ feat)
{
    int d = blockIdx.x; int j = threadIdx.x; // 64
    int o = offs[d];
    int deg = offs[d+1] - o;
    int total = deg + 1;
    float edst[4];
    #pragma unroll
    for (int h = 0; h < 4; ++h) edst[h] = ed2[d*4+h];
    float lmax[4] = {-1e30f,-1e30f,-1e30f,-1e30f};
    for (int idx = j; idx < total; idx += 64){
        int s = (idx < deg) ? csr[o + idx] : d;
        #pragma unroll
        for (int h = 0; h < 4; ++h)
            lmax[h] = fmaxf(lmax[h], leakyf_(es2[s*4+h] + edst[h]));
    }
    #pragma unroll
    for (int h = 0; h < 4; ++h)
        for (int m = 32; m; m >>= 1) lmax[h] = fmaxf(lmax[h], __shfl_xor(lmax[h], m));
    float lsum[4] = {0.f,0.f,0.f,0.f};
    float lnum[4] = {0.f,0.f,0.f,0.f};
    for (int idx = j; idx < total; idx += 64){
        int s = (idx < deg) ? csr[o + idx] : d;
        #pragma unroll
        for (int h = 0; h < 4; ++h){
            float e  = leakyf_(es2[s*4+h] + edst[h]);
            float ex = __expf(e - lmax[h]);
            lsum[h] += ex;
            lnum[h] += ex * hh2[s*4+h];
        }
    }
    #pragma unroll
    for (int h = 0; h < 4; ++h){
        for (int m = 32; m; m >>= 1){ lsum[h] += __shfl_xor(lsum[h], m); lnum[h] += __shfl_xor(lnum[h], m); }
    }
    if (j == 0){
        float sum = 0.f;
        #pragma unroll
        for (int h = 0; h < 4; ++h) sum += lnum[h] / lsum[h];
        feat[d] = sigmoidf_(0.25f*sum + bc2[0] + lv[d] + bl2[0]);
    }
}

// ---------- prep A1 (bf16, [row][k], row-major = ctrl's layout, no transpose) ----------
__global__ void k_prepA(const float* __restrict__ ctrl, const float* __restrict__ feat,
                        unsigned short* __restrict__ Abf)
{
    int col = blockIdx.x*256 + threadIdx.x;
    int row = blockIdx.y;
    if (col < 20000)
        Abf[(size_t)row*KA1 + col] = f2bf(ctrl[(size_t)row*20000 + col] + feat[col]);
}

// ---------- pert MLP -> writes Abf1 cols 20000..20063 (+ zero pad to 20095) ----------
__global__ void k_pert(const float* __restrict__ pert, const float* __restrict__ W1,
                       const float* __restrict__ b1, const float* __restrict__ W2,
                       const float* __restrict__ b2, unsigned short* __restrict__ Abf)
{
    int r = blockIdx.x; int t = threadIdx.x; // 128
    __shared__ float hid[128];
    float acc = 0.f;
    for (int k = 0; k < PD; ++k) acc += pert[r*PD + k] * W1[k*128 + t];
    hid[t] = sigmoidf_(acc + b1[t]);
    __syncthreads();
    if (t < 64){
        float a2 = 0.f;
        for (int k = 0; k < 128; ++k) a2 += hid[k] * W2[k*64 + t];
        Abf[(size_t)r*KA1 + 20000 + t] = f2bf(a2 + b2[t]);
    } else if (t < 96){
        Abf[(size_t)r*KA1 + 20000 + t] = 0;  // zero K-pad 20064..20095
    }
}

// ---------- pred GEMM1 (MFMA bf16): part[ks] = A[128 x Kchunk] @ W1 ----------
__global__ __launch_bounds__(256, 2)
void k_gemm1m(const unsigned short* __restrict__ Abf, const float* __restrict__ W1,
              float* __restrict__ part)
{
    int t = threadIdx.x;
    int lane = t & 63, wv = t >> 6;
    int lane16 = lane & 15, quad = lane >> 4, quad8 = quad * 8;
    int colbase = blockIdx.x * 64;
    int ks = blockIdx.y;
    int sbeg = (ks * NSTEP1) / KSPLIT1;
    int send = ((ks + 1) * NSTEP1) / KSPLIT1;
    int nsteps = send - sbeg;
    int kbeg = sbeg * 32;
    __shared__ unsigned short Bs[2][32*64];

    v4f acc[8];
    #pragma unroll
    for (int i = 0; i < 8; ++i) acc[i] = (v4f){0.f,0.f,0.f,0.f};

    int krow = t >> 3;           // 0..31
    int ng   = (t & 7) * 8;      // 0..56
    {
        int kg = kbeg + krow;
        short8 p;
        if (kg < 20064){
            float4 a = *(const float4*)(W1 + (size_t)kg*1024 + colbase + ng);
            float4 b = *(const float4*)(W1 + (size_t)kg*1024 + colbase + ng + 4);
            p[0]=(short)f2bf(a.x); p[1]=(short)f2bf(a.y); p[2]=(short)f2bf(a.z); p[3]=(short)f2bf(a.w);
            p[4]=(short)f2bf(b.x); p[5]=(short)f2bf(b.y); p[6]=(short)f2bf(b.z); p[7]=(short)f2bf(b.w);
        } else {
            p = (short8){0,0,0,0,0,0,0,0};
        }
        *(short8*)&Bs[0][krow*64 + ng] = p;
    }
    __syncthreads();

    int cur = 0;
    for (int s = 0; s < nsteps; ++s){
        int kg = kbeg + s*32;
        short8 bfrag;
        #pragma unroll
        for (int j = 0; j < 8; ++j)
            bfrag[j] = (short)Bs[cur][(quad8 + j)*64 + wv*16 + lane16];
        float w[8];
        bool more = (s + 1) < nsteps;
        if (more){
            int kn = kg + 32 + krow;
            if (kn < 20064){
                float4 a = *(const float4*)(W1 + (size_t)kn*1024 + colbase + ng);
                float4 b = *(const float4*)(W1 + (size_t)kn*1024 + colbase + ng + 4);
                w[0]=a.x; w[1]=a.y; w[2]=a.z; w[3]=a.w; w[4]=b.x; w[5]=b.y; w[6]=b.z; w[7]=b.w;
            } else {
                #pragma unroll
                for (int i = 0; i < 8; ++i) w[i] = 0.f;
            }
        }
        #pragma unroll
        for (int mt = 0; mt < 8; ++mt){
            short8 af = *(const short8*)(Abf + (size_t)(mt*16 + lane16)*KA1 + kg + quad8);
            acc[mt] = __builtin_amdgcn_mfma_f32_16x16x32_bf16(af, bfrag, acc[mt], 0, 0, 0);
        }
        if (more){
            short8 p;
            #pragma unroll
            for (int i = 0; i < 8; ++i) p[i] = (short)f2bf(w[i]);
            *(short8*)&Bs[cur^1][krow*64 + ng] = p;
        }
        __syncthreads();
        cur ^= 1;
    }
    float* dst = part + (size_t)ks * 131072;
    int col = colbase + wv*16 + lane16;
    #pragma unroll
    for (int mt = 0; mt < 8; ++mt)
        #pragma unroll
        for (int r = 0; r < 4; ++r)
            dst[(size_t)(mt*16 + quad*4 + r)*1024 + col] = acc[mt][r];
}

// ---------- reduce partials + bias + sigmoid -> hidbf[128][1024] bf16 ----------
__global__ void k_reduce(const float* __restrict__ part, const float* __restrict__ b1,
                         unsigned short* __restrict__ hidbf)
{
    int row = blockIdx.x;                       // 0..127
    int col = blockIdx.y*256 + threadIdx.x;     // 0..1023
    float s = 0.f;
    #pragma unroll
    for (int ks = 0; ks < KSPLIT1; ++ks)
        s += part[(size_t)ks*131072 + (size_t)row*1024 + col];
    hidbf[(size_t)row*1024 + col] = f2bf(sigmoidf_(s + b1[col]));
}

// ---------- pred GEMM2 (MFMA bf16): out = hid[128x1024] @ W2 + b2 ----------
__global__ __launch_bounds__(256, 2)
void k_gemm2m(const unsigned short* __restrict__ hidbf, const float* __restrict__ W2,
              const float* __restrict__ b2, float* __restrict__ out)
{
    int t = threadIdx.x;
    int lane = t & 63, wv = t >> 6;
    int lane16 = lane & 15, quad = lane >> 4, quad8 = quad * 8;
    int colbase = blockIdx.x * 64;
    int rbase   = blockIdx.y * 64;
    __shared__ unsigned short Bs[2][32*64];

    v4f acc[4];
    #pragma unroll
    for (int i = 0; i < 4; ++i) acc[i] = (v4f){0.f,0.f,0.f,0.f};

    int krow = t >> 3;
    int ng   = (t & 7) * 8;
    bool cv = (colbase + ng) < 20000;   // 8-col granule, 20000 % 8 == 0
    {
        short8 p = (short8){0,0,0,0,0,0,0,0};
        if (cv){
            float4 a = *(const float4*)(W2 + (size_t)krow*20000 + colbase + ng);
            float4 b = *(const float4*)(W2 + (size_t)krow*20000 + colbase + ng + 4);
            p[0]=(short)f2bf(a.x); p[1]=(short)f2bf(a.y); p[2]=(short)f2bf(a.z); p[3]=(short)f2bf(a.w);
            p[4]=(short)f2bf(b.x); p[5]=(short)f2bf(b.y); p[6]=(short)f2bf(b.z); p[7]=(short)f2bf(b.w);
        }
        *(short8*)&Bs[0][krow*64 + ng] = p;
    }
    __syncthreads();

    int cur = 0;
    for (int s = 0; s < 32; ++s){
        int kg = s*32;
        short8 bfrag;
        #pragma unroll
        for (int j = 0; j < 8; ++j)
            bfrag[j] = (short)Bs[cur][(quad8 + j)*64 + wv*16 + lane16];
        float w[8];
        bool more = s < 31;
        if (more){
            if (cv){
                int kn = kg + 32 + krow;
                float4 a = *(const float4*)(W2 + (size_t)kn*20000 + colbase + ng);
                float4 b = *(const float4*)(W2 + (size_t)kn*20000 + colbase + ng + 4);
                w[0]=a.x; w[1]=a.y; w[2]=a.z; w[3]=a.w; w[4]=b.x; w[5]=b.y; w[6]=b.z; w[7]=b.w;
            } else {
                #pragma unroll
                for (int i = 0; i < 8; ++i) w[i] = 0.f;
            }
        }
        #pragma unroll
        for (int mt = 0; mt < 4; ++mt){
            short8 af = *(const short8*)(hidbf + (size_t)(rbase + mt*16 + lane16)*KA2 + kg + quad8);
            acc[mt] = __builtin_amdgcn_mfma_f32_16x16x32_bf16(af, bfrag, acc[mt], 0, 0, 0);
        }
        if (more){
            short8 p;
            #pragma unroll
            for (int i = 0; i < 8; ++i) p[i] = (short)f2bf(w[i]);
            *(short8*)&Bs[cur^1][krow*64 + ng] = p;
        }
        __syncthreads();
        cur ^= 1;
    }
    int col = colbase + wv*16 + lane16;
    if (col < 20000){
        float bb = b2[col];
        #pragma unroll
        for (int mt = 0; mt < 4; ++mt)
            #pragma unroll
            for (int r = 0; r < 4; ++r)
                out[(size_t)(rbase + mt*16 + quad*4 + r)*20000 + col] = acc[mt][r] + bb;
    }
}

extern "C" void kernel_launch(void* const* d_in, const int* in_sizes, int n_in,
                              void* d_out, int out_size, void* d_ws, size_t ws_size,
                              hipStream_t stream)
{
    const float* x    = (const float*)d_in[0];
    const int*   ei   = (const int*)  d_in[1];
    const int*   pos  = (const int*)  d_in[2];
    const float* ctrl = (const float*)d_in[3];
    const float* pert = (const float*)d_in[4];
    const float* ge   = (const float*)d_in[5];
    const float* c1W  = (const float*)d_in[6];
    const float* c1as = (const float*)d_in[7];
    const float* c1ad = (const float*)d_in[8];
    const float* c1b  = (const float*)d_in[9];
    const float* l1W  = (const float*)d_in[10];
    const float* l1b  = (const float*)d_in[11];
    const float* c2W  = (const float*)d_in[12];
    const float* c2as = (const float*)d_in[13];
    const float* c2ad = (const float*)d_in[14];
    const float* c2b  = (const float*)d_in[15];
    const float* l2W  = (const float*)d_in[16];
    const float* l2b  = (const float*)d_in[17];
    const float* pW1  = (const float*)d_in[18];
    const float* pb1  = (const float*)d_in[19];
    const float* pW2  = (const float*)d_in[20];
    const float* pb2  = (const float*)d_in[21];
    const float* prW1 = (const float*)d_in[22];
    const float* prb1 = (const float*)d_in[23];
    const float* prW2 = (const float*)d_in[24];
    const float* prb2 = (const float*)d_in[25];
    float* out = (float*)d_out;

    char* ws = (char*)d_ws;
    size_t off = 0;
    auto alloc = [&](size_t bytes)->void*{
        void* pp = ws + off;
        off += (bytes + 255) & ~(size_t)255;
        return pp;
    };
    unsigned short* hcb  = (unsigned short*)alloc((size_t)G*256*2);  // 10.24 MB
    float* hlin = (float*)alloc((size_t)G*64*4);                      // 5.12 MB
    float* es1  = (float*)alloc((size_t)G*4*4);
    float* ed1  = (float*)alloc((size_t)G*4*4);
    float* hh2  = (float*)alloc((size_t)G*4*4);
    float* es2  = (float*)alloc((size_t)G*4*4);
    float* ed2  = (float*)alloc((size_t)G*4*4);
    float* lv   = (float*)alloc((size_t)G*4);
    float* feat = (float*)alloc((size_t)G*4);
    unsigned short* hidbf = (unsigned short*)alloc((size_t)128*KA2*2);
    unsigned short* Abf1  = (unsigned short*)alloc((size_t)128*KA1*2);   // 5.1 MB
    float* part = (float*)alloc((size_t)KSPLIT1*131072*4);               // 16.8 MB
    int*   cnt  = (int*)alloc((size_t)G*4);
    int*   offs = (int*)alloc((size_t)(G+1)*4);
    int*   cur  = (int*)alloc((size_t)G*4);
    int*   csr  = (int*)alloc((size_t)E_EDGES*4);

    hipMemsetAsync(cnt, 0, (size_t)G*4, stream);

    k_hist   <<<(E_EDGES+255)/256, 256, 0, stream>>>(ei, cnt);
    k_scan   <<<1, 1024, 0, stream>>>(cnt, offs, cur);
    k_scatter<<<(E_EDGES+255)/256, 256, 0, stream>>>(ei, cur, csr);

    k_hc   <<<(G + ROWS_HC - 1)/ROWS_HC, 320, 0, stream>>>(x, pos, ge, c1W, l1W, c1as, c1ad,
                                         hcb, hlin, es1, ed1);
    k_gat1 <<<G/4, 256, 0, stream>>>(hcb, hlin, es1, ed1, offs, csr, c1b, l1b,
                                     c2W, c2as, c2ad, l2W, hh2, es2, ed2, lv);
    k_gat2 <<<G, 64, 0, stream>>>(hh2, es2, ed2, offs, csr, lv, c2b, l2b, feat);

    dim3 gp(79, 128);
    k_prepA<<<gp, 256, 0, stream>>>(ctrl, feat, Abf1);
    k_pert <<<BATCH, 128, 0, stream>>>(pert, pW1, pb1, pW2, pb2, Abf1);

    dim3 g1(16, KSPLIT1);
    k_gemm1m<<<g1, 256, 0, stream>>>(Abf1, prW1, part);
    dim3 gr(128, 4);
    k_reduce<<<gr, 256, 0, stream>>>(part, prb1, hidbf);
    dim3 g2(313, 2);
    k_gemm2m<<<g2, 256, 0, stream>>>(hidbf, prW2, prb2, out);
}

// Round 16
// 590.711 us; speedup vs baseline: 1.1152x; 1.0075x over previous
//
#include <hip/hip_runtime.h>
#include <math.h>

#define G 20000
#define E_EDGES 640000
#define HID 64
#define NHEAD 4
#define BATCH 128
#define PD 600
#define NEG 0.2f
#define MAXN 128           // per-dst neighbor cap (deg ~ Poisson(32), max ~70)

#define KA1 20096          // 20064 padded to multiple of 32
#define NSTEP1 628         // 20096 / 32
#define KSPLIT1 32
#define KA2 1024
#define KSPLIT2 4          // R15: gemm2 K-split: 4 chunks of 256 (8 steps of 32)
#define P2STRIDE 2560000   // 128*20000

#define ROWS_HC 16         // rows per k_hc block: 1250 blocks

typedef float v4f __attribute__((ext_vector_type(4)));
typedef short short8 __attribute__((ext_vector_type(8)));

__device__ __forceinline__ float sigmoidf_(float x){ return 1.0f/(1.0f+__expf(-x)); }
__device__ __forceinline__ float leakyf_(float x){ return x>=0.f ? x : NEG*x; }
__device__ __forceinline__ unsigned short f2bf(float f){
    unsigned int u = __float_as_uint(f);
    return (unsigned short)((u + 0x7FFFu + ((u >> 16) & 1u)) >> 16);
}
__device__ __forceinline__ float bf2f(unsigned short b){
    return __uint_as_float(((unsigned int)b) << 16);
}

// ---------- Stage 1 fused: hc/es/ed.  ROWS_HC rows/block, 320 threads. ----------
// R14-verified (76.5us). VALUBusy ~26% across 1-acc and 4-acc variants.
__global__ __launch_bounds__(320)
void k_hc(const float* __restrict__ x, const int* __restrict__ pos,
          const float* __restrict__ ge, const float* __restrict__ Wc,
          const float* __restrict__ Wl, const float* __restrict__ as_,
          const float* __restrict__ ad_,
          unsigned short* __restrict__ hcb, float* __restrict__ hlin,
          float* __restrict__ es, float* __restrict__ ed)
{
    int t = threadIdx.x;                 // 320
    int rb = blockIdx.x * ROWS_HC;       // grid 1250
    __shared__ float xc[ROWS_HC][68];    // row stride 272B (16B aligned)
    for (int l = t; l < ROWS_HC*65; l += 320){
        int r = l / 65, k = l - r*65;
        int row = rb + r;
        float v = 0.f;
        if (row < G) v = (k == 0) ? x[row] : ge[pos[row]*HID + (k-1)];
        xc[r][k] = v;
    }
    float wcol[65];
    if (t < 256){
        #pragma unroll
        for (int k = 0; k < 65; ++k) wcol[k] = Wc[k*256 + t];
    } else {
        int c = t - 256;
        #pragma unroll
        for (int k = 0; k < 65; ++k) wcol[k] = Wl[k*64 + c];
    }
    float a_s = 0.f, a_d = 0.f;
    if (t < 256){ a_s = as_[t]; a_d = ad_[t]; }
    __syncthreads();

    int nrow = G - rb; if (nrow > ROWS_HC) nrow = ROWS_HC;
    for (int r = 0; r < nrow; ++r){
        int row = rb + r;
        const float4* xr = (const float4*)&xc[r][0];
        float b0 = 0.f, b1 = 0.f, b2 = 0.f, b3 = 0.f;
        #pragma unroll
        for (int k4 = 0; k4 < 16; ++k4){
            float4 v = xr[k4];
            b0 += v.x*wcol[4*k4];
            b1 += v.y*wcol[4*k4+1];
            b2 += v.z*wcol[4*k4+2];
            b3 += v.w*wcol[4*k4+3];
        }
        float acc = (b0 + b1) + (b2 + b3) + xc[r][64] * wcol[64];
        if (t < 256){
            hcb[(size_t)row*256 + t] = f2bf(acc);
            float v1 = acc * a_s, v2 = acc * a_d;
            #pragma unroll
            for (int m = 32; m; m >>= 1){ v1 += __shfl_xor(v1, m); v2 += __shfl_xor(v2, m); }
            if ((t & 63) == 0){ int h = t >> 6; es[row*4+h] = v1; ed[row*4+h] = v2; }
        } else {
            hlin[(size_t)row*64 + (t - 256)] = acc;
        }
    }
}

// ---------- CSR build ----------
__global__ void k_hist(const int* __restrict__ ei, int* __restrict__ cnt){
    int e = blockIdx.x*blockDim.x + threadIdx.x;
    if (e < E_EDGES) atomicAdd(&cnt[ei[E_EDGES + e]], 1);
}
__global__ void k_scan(const int* __restrict__ cnt, int* __restrict__ offs,
                       int* __restrict__ cur)
{
    __shared__ int ts[1024];
    int t = threadIdx.x;
    int base = t * 20;
    int loc[20];
    int s = 0;
    #pragma unroll
    for (int j = 0; j < 20; ++j){
        int i = base + j;
        int v = (i < G) ? cnt[i] : 0;
        loc[j] = s; s += v;
    }
    ts[t] = s;
    __syncthreads();
    for (int off = 1; off < 1024; off <<= 1){
        int add = (t >= off) ? ts[t - off] : 0;
        __syncthreads();
        ts[t] += add;
        __syncthreads();
    }
    int tb = (t == 0) ? 0 : ts[t - 1];
    #pragma unroll
    for (int j = 0; j < 20; ++j){
        int i = base + j;
        if (i < G){ int o = tb + loc[j]; offs[i] = o; cur[i] = o; }
    }
    if (t == 0) offs[G] = ts[1023];
}
__global__ void k_scatter(const int* __restrict__ ei, int* __restrict__ cur, int* __restrict__ csr){
    int e = blockIdx.x*blockDim.x + threadIdx.x;
    if (e < E_EDGES){
        int d = ei[E_EDGES + e];
        int p = atomicAdd(&cur[d], 1);
        csr[p] = ei[e];
    }
}

// ---------- GAT1 apply + FUSED conv2prep (R14-verified) ----------
__global__ __launch_bounds__(256)
void k_gat1(const unsigned short* __restrict__ hcb, const float* __restrict__ hlin,
            const float* __restrict__ es, const float* __restrict__ ed,
            const int* __restrict__ offs, const int* __restrict__ csr,
            const float* __restrict__ bc1, const float* __restrict__ bl1,
            const float* __restrict__ W2c, const float* __restrict__ as2,
            const float* __restrict__ ad2, const float* __restrict__ Wl2,
            float* __restrict__ hh2, float* __restrict__ es2o,
            float* __restrict__ ed2o, float* __restrict__ lv)
{
    int t = threadIdx.x;
    int lane = t & 63, wv = t >> 6;
    int d = blockIdx.x * 4 + wv;            // grid 5000, exact
    __shared__ float4 wcache[4][MAXN];      // normalized per-head weights
    __shared__ int    wsrc[4][MAXN];
    int o = offs[d];
    int deg = offs[d+1] - o;
    int total = deg + 1;                    // + self loop
    if (total > MAXN) total = MAXN;
    float4 edv = *(const float4*)(ed + d*4);

    // ---- scores: slot0 = lane, slot1 = lane+64 ----
    float s0x=-1e30f, s0y=-1e30f, s0z=-1e30f, s0w=-1e30f;
    float s1x=-1e30f, s1y=-1e30f, s1z=-1e30f, s1w=-1e30f;
    if (lane < total){
        int s = (lane < deg) ? csr[o + lane] : d;
        wsrc[wv][lane] = s;
        float4 ev = *(const float4*)(es + s*4);
        s0x = leakyf_(ev.x + edv.x); s0y = leakyf_(ev.y + edv.y);
        s0z = leakyf_(ev.z + edv.z); s0w = leakyf_(ev.w + edv.w);
    }
    int i1 = lane + 64;
    if (i1 < total){
        int s = (i1 < deg) ? csr[o + i1] : d;
        wsrc[wv][i1] = s;
        float4 ev = *(const float4*)(es + s*4);
        s1x = leakyf_(ev.x + edv.x); s1y = leakyf_(ev.y + edv.y);
        s1z = leakyf_(ev.z + edv.z); s1w = leakyf_(ev.w + edv.w);
    }
    // ---- per-head max over both slots, then wave ----
    float m0 = fmaxf(s0x, s1x), m1 = fmaxf(s0y, s1y);
    float m2 = fmaxf(s0z, s1z), m3 = fmaxf(s0w, s1w);
    #pragma unroll
    for (int m = 32; m; m >>= 1){
        m0 = fmaxf(m0, __shfl_xor(m0, m)); m1 = fmaxf(m1, __shfl_xor(m1, m));
        m2 = fmaxf(m2, __shfl_xor(m2, m)); m3 = fmaxf(m3, __shfl_xor(m3, m));
    }
    // ---- exp (inactive slots -> 0) ----
    float e0x = __expf(s0x - m0), e0y = __expf(s0y - m1);
    float e0z = __expf(s0z - m2), e0w = __expf(s0w - m3);
    float e1x = __expf(s1x - m0), e1y = __expf(s1y - m1);
    float e1z = __expf(s1z - m2), e1w = __expf(s1w - m3);
    float q0 = e0x + e1x, q1 = e0y + e1y, q2 = e0z + e1z, q3 = e0w + e1w;
    #pragma unroll
    for (int m = 32; m; m >>= 1){
        q0 += __shfl_xor(q0, m); q1 += __shfl_xor(q1, m);
        q2 += __shfl_xor(q2, m); q3 += __shfl_xor(q3, m);
    }
    float inv0 = 1.0f/q0, inv1 = 1.0f/q1, inv2 = 1.0f/q2, inv3 = 1.0f/q3;
    if (lane < total) wcache[wv][lane] = make_float4(e0x*inv0, e0y*inv1, e0z*inv2, e0w*inv3);
    if (i1   < total) wcache[wv][i1]   = make_float4(e1x*inv0, e1y*inv1, e1z*inv2, e1w*inv3);
    __syncthreads();     // one barrier

    // ---- gather: lane owns flat cols 4u..4u+3 (head u>>4) ----
    int u = lane;
    int h = u >> 4;
    float a0=0.f, a1=0.f, a2=0.f, a3=0.f;
    uint2 v; float al;
    {
        int s = wsrc[wv][0];
        al = ((const float*)&wcache[wv][0])[h];
        v = *(const uint2*)(hcb + (size_t)s*256 + u*4);
    }
    for (int idx = 0; idx < total; ){
        uint2 vc = v; float ac = al;
        int nx = idx + 1;
        if (nx < total){                 // wave-uniform
            int s2 = wsrc[wv][nx];
            al = ((const float*)&wcache[wv][nx])[h];
            v = *(const uint2*)(hcb + (size_t)s2*256 + u*4);
        }
        a0 += ac * __uint_as_float(vc.x << 16);
        a1 += ac * __uint_as_float(vc.x & 0xFFFF0000u);
        a2 += ac * __uint_as_float(vc.y << 16);
        a3 += ac * __uint_as_float(vc.y & 0xFFFF0000u);
        idx = nx;
    }
    // ---- head-mean: after these, ALL lanes hold sums for cols 4*(lane&15)..+3 ----
    a0 += __shfl_xor(a0, 16); a1 += __shfl_xor(a1, 16);
    a2 += __shfl_xor(a2, 16); a3 += __shfl_xor(a3, 16);
    a0 += __shfl_xor(a0, 32); a1 += __shfl_xor(a1, 32);
    a2 += __shfl_xor(a2, 32); a3 += __shfl_xor(a3, 32);

    // ---- fused epilogue: h1 in-register, conv2prep reductions ----
    int cb = (lane & 15) * 4;            // this lane's col base (dup x4 across wave)
    float4 hl  = *(const float4*)(hlin + (size_t)d*64 + cb);
    float4 bcv = *(const float4*)(bc1 + cb);
    float4 blv = *(const float4*)(bl1 + cb);
    float h0 = sigmoidf_(0.25f*a0 + bcv.x + hl.x + blv.x);
    float h1v= sigmoidf_(0.25f*a1 + bcv.y + hl.y + blv.y);
    float h2v= sigmoidf_(0.25f*a2 + bcv.z + hl.z + blv.z);
    float h3v= sigmoidf_(0.25f*a3 + bcv.w + hl.w + blv.w);
    // conv2 partials over this lane's 4 cols, for each head j
    float p0 = h0*W2c[cb*4+0] + h1v*W2c[(cb+1)*4+0] + h2v*W2c[(cb+2)*4+0] + h3v*W2c[(cb+3)*4+0];
    float p1 = h0*W2c[cb*4+1] + h1v*W2c[(cb+1)*4+1] + h2v*W2c[(cb+2)*4+1] + h3v*W2c[(cb+3)*4+1];
    float p2 = h0*W2c[cb*4+2] + h1v*W2c[(cb+1)*4+2] + h2v*W2c[(cb+2)*4+2] + h3v*W2c[(cb+3)*4+2];
    float p3 = h0*W2c[cb*4+3] + h1v*W2c[(cb+1)*4+3] + h2v*W2c[(cb+2)*4+3] + h3v*W2c[(cb+3)*4+3];
    float pl = h0*Wl2[cb] + h1v*Wl2[cb+1] + h2v*Wl2[cb+2] + h3v*Wl2[cb+3];
    #pragma unroll
    for (int m = 1; m <= 8; m <<= 1){
        p0 += __shfl_xor(p0, m); p1 += __shfl_xor(p1, m);
        p2 += __shfl_xor(p2, m); p3 += __shfl_xor(p3, m);
        pl += __shfl_xor(pl, m);
    }
    if (lane == 0){
        hh2[d*4+0] = p0; hh2[d*4+1] = p1; hh2[d*4+2] = p2; hh2[d*4+3] = p3;
        es2o[d*4+0] = p0*as2[0]; es2o[d*4+1] = p1*as2[1];
        es2o[d*4+2] = p2*as2[2]; es2o[d*4+3] = p3*as2[3];
        ed2o[d*4+0] = p0*ad2[0]; ed2o[d*4+1] = p1*ad2[1];
        ed2o[d*4+2] = p2*ad2[2]; ed2o[d*4+3] = p3*ad2[3];
        lv[d] = pl;
    }
}

// ---------- GAT2 apply ----------
__global__ void k_gat2(const float* __restrict__ hh2, const float* __restrict__ es2,
                       const float* __restrict__ ed2, const int* __restrict__ offs,
                       const int* __restrict__ csr, const float* __restrict__ lv,
                       const float* __restrict__ bc2, const float* __restrict__ bl2,
                       float* __restrict__ feat)
{
    int d = blockIdx.x; int j = threadIdx.x; // 64
    int o = offs[d];
    int deg = offs[d+1] - o;
    int total = deg + 1;
    float edst[4];
    #pragma unroll
    for (int h = 0; h < 4; ++h) edst[h] = ed2[d*4+h];
    float lmax[4] = {-1e30f,-1e30f,-1e30f,-1e30f};
    for (int idx = j; idx < total; idx += 64){
        int s = (idx < deg) ? csr[o + idx] : d;
        #pragma unroll
        for (int h = 0; h < 4; ++h)
            lmax[h] = fmaxf(lmax[h], leakyf_(es2[s*4+h] + edst[h]));
    }
    #pragma unroll
    for (int h = 0; h < 4; ++h)
        for (int m = 32; m; m >>= 1) lmax[h] = fmaxf(lmax[h], __shfl_xor(lmax[h], m));
    float lsum[4] = {0.f,0.f,0.f,0.f};
    float lnum[4] = {0.f,0.f,0.f,0.f};
    for (int idx = j; idx < total; idx += 64){
        int s = (idx < deg) ? csr[o + idx] : d;
        #pragma unroll
        for (int h = 0; h < 4; ++h){
            float e  = leakyf_(es2[s*4+h] + edst[h]);
            float ex = __expf(e - lmax[h]);
            lsum[h] += ex;
            lnum[h] += ex * hh2[s*4+h];
        }
    }
    #pragma unroll
    for (int h = 0; h < 4; ++h){
        for (int m = 32; m; m >>= 1){ lsum[h] += __shfl_xor(lsum[h], m); lnum[h] += __shfl_xor(lnum[h], m); }
    }
    if (j == 0){
        float sum = 0.f;
        #pragma unroll
        for (int h = 0; h < 4; ++h) sum += lnum[h] / lsum[h];
        feat[d] = sigmoidf_(0.25f*sum + bc2[0] + lv[d] + bl2[0]);
    }
}

// ---------- prep A1 (bf16, [row][k], row-major = ctrl's layout, no transpose) ----------
__global__ void k_prepA(const float* __restrict__ ctrl, const float* __restrict__ feat,
                        unsigned short* __restrict__ Abf)
{
    int col = blockIdx.x*256 + threadIdx.x;
    int row = blockIdx.y;
    if (col < 20000)
        Abf[(size_t)row*KA1 + col] = f2bf(ctrl[(size_t)row*20000 + col] + feat[col]);
}

// ---------- pert MLP -> writes Abf1 cols 20000..20063 (+ zero pad to 20095) ----------
__global__ void k_pert(const float* __restrict__ pert, const float* __restrict__ W1,
                       const float* __restrict__ b1, const float* __restrict__ W2,
                       const float* __restrict__ b2, unsigned short* __restrict__ Abf)
{
    int r = blockIdx.x; int t = threadIdx.x; // 128
    __shared__ float hid[128];
    float acc = 0.f;
    for (int k = 0; k < PD; ++k) acc += pert[r*PD + k] * W1[k*128 + t];
    hid[t] = sigmoidf_(acc + b1[t]);
    __syncthreads();
    if (t < 64){
        float a2 = 0.f;
        for (int k = 0; k < 128; ++k) a2 += hid[k] * W2[k*64 + t];
        Abf[(size_t)r*KA1 + 20000 + t] = f2bf(a2 + b2[t]);
    } else if (t < 96){
        Abf[(size_t)r*KA1 + 20000 + t] = 0;  // zero K-pad 20064..20095
    }
}

// ---------- pred GEMM1 (MFMA bf16): part[ks] = A[128 x Kchunk] @ W1 ----------
__global__ __launch_bounds__(256, 2)
void k_gemm1m(const unsigned short* __restrict__ Abf, const float* __restrict__ W1,
              float* __restrict__ part)
{
    int t = threadIdx.x;
    int lane = t & 63, wv = t >> 6;
    int lane16 = lane & 15, quad = lane >> 4, quad8 = quad * 8;
    int colbase = blockIdx.x * 64;
    int ks = blockIdx.y;
    int sbeg = (ks * NSTEP1) / KSPLIT1;
    int send = ((ks + 1) * NSTEP1) / KSPLIT1;
    int nsteps = send - sbeg;
    int kbeg = sbeg * 32;
    __shared__ unsigned short Bs[2][32*64];

    v4f acc[8];
    #pragma unroll
    for (int i = 0; i < 8; ++i) acc[i] = (v4f){0.f,0.f,0.f,0.f};

    int krow = t >> 3;           // 0..31
    int ng   = (t & 7) * 8;      // 0..56
    {
        int kg = kbeg + krow;
        short8 p;
        if (kg < 20064){
            float4 a = *(const float4*)(W1 + (size_t)kg*1024 + colbase + ng);
            float4 b = *(const float4*)(W1 + (size_t)kg*1024 + colbase + ng + 4);
            p[0]=(short)f2bf(a.x); p[1]=(short)f2bf(a.y); p[2]=(short)f2bf(a.z); p[3]=(short)f2bf(a.w);
            p[4]=(short)f2bf(b.x); p[5]=(short)f2bf(b.y); p[6]=(short)f2bf(b.z); p[7]=(short)f2bf(b.w);
        } else {
            p = (short8){0,0,0,0,0,0,0,0};
        }
        *(short8*)&Bs[0][krow*64 + ng] = p;
    }
    __syncthreads();

    int cur = 0;
    for (int s = 0; s < nsteps; ++s){
        int kg = kbeg + s*32;
        short8 bfrag;
        #pragma unroll
        for (int j = 0; j < 8; ++j)
            bfrag[j] = (short)Bs[cur][(quad8 + j)*64 + wv*16 + lane16];
        float w[8];
        bool more = (s + 1) < nsteps;
        if (more){
            int kn = kg + 32 + krow;
            if (kn < 20064){
                float4 a = *(const float4*)(W1 + (size_t)kn*1024 + colbase + ng);
                float4 b = *(const float4*)(W1 + (size_t)kn*1024 + colbase + ng + 4);
                w[0]=a.x; w[1]=a.y; w[2]=a.z; w[3]=a.w; w[4]=b.x; w[5]=b.y; w[6]=b.z; w[7]=b.w;
            } else {
                #pragma unroll
                for (int i = 0; i < 8; ++i) w[i] = 0.f;
            }
        }
        #pragma unroll
        for (int mt = 0; mt < 8; ++mt){
            short8 af = *(const short8*)(Abf + (size_t)(mt*16 + lane16)*KA1 + kg + quad8);
            acc[mt] = __builtin_amdgcn_mfma_f32_16x16x32_bf16(af, bfrag, acc[mt], 0, 0, 0);
        }
        if (more){
            short8 p;
            #pragma unroll
            for (int i = 0; i < 8; ++i) p[i] = (short)f2bf(w[i]);
            *(short8*)&Bs[cur^1][krow*64 + ng] = p;
        }
        __syncthreads();
        cur ^= 1;
    }
    float* dst = part + (size_t)ks * 131072;
    int col = colbase + wv*16 + lane16;
    #pragma unroll
    for (int mt = 0; mt < 8; ++mt)
        #pragma unroll
        for (int r = 0; r < 4; ++r)
            dst[(size_t)(mt*16 + quad*4 + r)*1024 + col] = acc[mt][r];
}

// ---------- reduce partials + bias + sigmoid -> hidbf[128][1024] bf16 ----------
__global__ void k_reduce(const float* __restrict__ part, const float* __restrict__ b1,
                         unsigned short* __restrict__ hidbf)
{
    int row = blockIdx.x;                       // 0..127
    int col = blockIdx.y*256 + threadIdx.x;     // 0..1023
    float s = 0.f;
    #pragma unroll
    for (int ks = 0; ks < KSPLIT1; ++ks)
        s += part[(size_t)ks*131072 + (size_t)row*1024 + col];
    hidbf[(size_t)row*1024 + col] = f2bf(sigmoidf_(s + b1[col]));
}

// ---------- pred GEMM2 (MFMA bf16, R15 K-split x4): part2[ks] = hid @ W2[kchunk] ----------
// Old: grid (313,2)=626 blocks, 32 barrier-serialized K-steps, occ 23%, MfmaUtil 2.5%,
// 1.28M LDS bank conflicts, 77us vs ~13us HBM floor. New: grid (626,4)=2504 blocks
// (x = colbase*2+rbase pairs adjacent -> shared W2 tile in L2; y = K-chunk of 256),
// 8 steps/block, partials to part2 + k_reduce2. Bs reads XOR-swizzled: col^(quad<<4)
// puts the 4 quads on 4 disjoint bank octets (was 8-way same-bank). Bias moved to reduce2.
__global__ __launch_bounds__(256, 2)
void k_gemm2m(const unsigned short* __restrict__ hidbf, const float* __restrict__ W2,
              float* __restrict__ part2)
{
    int t = threadIdx.x;
    int lane = t & 63, wv = t >> 6;
    int lane16 = lane & 15, quad = lane >> 4, quad8 = quad * 8;
    int colbase = (blockIdx.x >> 1) * 64;
    int rbase   = (blockIdx.x & 1) * 64;
    int ks      = blockIdx.y;            // 0..3
    int kbeg    = ks * 256;
    __shared__ unsigned short Bs[2][32*64];

    v4f acc[4];
    #pragma unroll
    for (int i = 0; i < 4; ++i) acc[i] = (v4f){0.f,0.f,0.f,0.f};

    int krow = t >> 3;                   // 0..31
    int ng   = (t & 7) * 8;              // 0..56
    int wng  = ng ^ ((krow >> 3) << 4);  // swizzled write col (8-aligned, 16B ok)
    bool cv = (colbase + ng) < 20000;    // 8-col granule, 20000 % 8 == 0
    {
        short8 p = (short8){0,0,0,0,0,0,0,0};
        if (cv){
            int kg = kbeg + krow;        // < 1024 always
            float4 a = *(const float4*)(W2 + (size_t)kg*20000 + colbase + ng);
            float4 b = *(const float4*)(W2 + (size_t)kg*20000 + colbase + ng + 4);
            p[0]=(short)f2bf(a.x); p[1]=(short)f2bf(a.y); p[2]=(short)f2bf(a.z); p[3]=(short)f2bf(a.w);
            p[4]=(short)f2bf(b.x); p[5]=(short)f2bf(b.y); p[6]=(short)f2bf(b.z); p[7]=(short)f2bf(b.w);
        }
        *(short8*)&Bs[0][krow*64 + wng] = p;
    }
    __syncthreads();

    int swcol = (wv*16 + lane16) ^ (quad << 4);   // swizzled read col for rows quad8+j
    int cur = 0;
    for (int s = 0; s < 8; ++s){
        int kg = kbeg + s*32;
        short8 bfrag;
        #pragma unroll
        for (int j = 0; j < 8; ++j)
            bfrag[j] = (short)Bs[cur][(quad8 + j)*64 + swcol];
        float w[8];
        bool more = s < 7;
        if (more){
            if (cv){
                int kn = kg + 32 + krow;   // <= kbeg+255 < 1024, no guard needed
                float4 a = *(const float4*)(W2 + (size_t)kn*20000 + colbase + ng);
                float4 b = *(const float4*)(W2 + (size_t)kn*20000 + colbase + ng + 4);
                w[0]=a.x; w[1]=a.y; w[2]=a.z; w[3]=a.w; w[4]=b.x; w[5]=b.y; w[6]=b.z; w[7]=b.w;
            } else {
                #pragma unroll
                for (int i = 0; i < 8; ++i) w[i] = 0.f;
            }
        }
        #pragma unroll
        for (int mt = 0; mt < 4; ++mt){
            short8 af = *(const short8*)(hidbf + (size_t)(rbase + mt*16 + lane16)*KA2 + kg + quad8);
            acc[mt] = __builtin_amdgcn_mfma_f32_16x16x32_bf16(af, bfrag, acc[mt], 0, 0, 0);
        }
        if (more){
            short8 p;
            #pragma unroll
            for (int i = 0; i < 8; ++i) p[i] = (short)f2bf(w[i]);
            *(short8*)&Bs[cur^1][krow*64 + wng] = p;
        }
        __syncthreads();
        cur ^= 1;
    }
    float* dst = part2 + (size_t)ks * P2STRIDE;
    int col = colbase + wv*16 + lane16;
    if (col < 20000){
        #pragma unroll
        for (int mt = 0; mt < 4; ++mt)
            #pragma unroll
            for (int r = 0; r < 4; ++r)
                dst[(size_t)(rbase + mt*16 + quad*4 + r)*20000 + col] = acc[mt][r];
    }
}

// ---------- reduce gemm2 partials + bias -> out ----------
__global__ void k_reduce2(const float* __restrict__ part2, const float* __restrict__ b2,
                          float* __restrict__ out)
{
    int row = blockIdx.x;                       // 0..127
    int col = blockIdx.y*256 + threadIdx.x;     // 79 blocks -> guard
    if (col < 20000){
        float s = 0.f;
        #pragma unroll
        for (int ks = 0; ks < KSPLIT2; ++ks)
            s += part2[(size_t)ks*P2STRIDE + (size_t)row*20000 + col];
        out[(size_t)row*20000 + col] = s + b2[col];
    }
}

extern "C" void kernel_launch(void* const* d_in, const int* in_sizes, int n_in,
                              void* d_out, int out_size, void* d_ws, size_t ws_size,
                              hipStream_t stream)
{
    const float* x    = (const float*)d_in[0];
    const int*   ei   = (const int*)  d_in[1];
    const int*   pos  = (const int*)  d_in[2];
    const float* ctrl = (const float*)d_in[3];
    const float* pert = (const float*)d_in[4];
    const float* ge   = (const float*)d_in[5];
    const float* c1W  = (const float*)d_in[6];
    const float* c1as = (const float*)d_in[7];
    const float* c1ad = (const float*)d_in[8];
    const float* c1b  = (const float*)d_in[9];
    const float* l1W  = (const float*)d_in[10];
    const float* l1b  = (const float*)d_in[11];
    const float* c2W  = (const float*)d_in[12];
    const float* c2as = (const float*)d_in[13];
    const float* c2ad = (const float*)d_in[14];
    const float* c2b  = (const float*)d_in[15];
    const float* l2W  = (const float*)d_in[16];
    const float* l2b  = (const float*)d_in[17];
    const float* pW1  = (const float*)d_in[18];
    const float* pb1  = (const float*)d_in[19];
    const float* pW2  = (const float*)d_in[20];
    const float* pb2  = (const float*)d_in[21];
    const float* prW1 = (const float*)d_in[22];
    const float* prb1 = (const float*)d_in[23];
    const float* prW2 = (const float*)d_in[24];
    const float* prb2 = (const float*)d_in[25];
    float* out = (float*)d_out;

    char* ws = (char*)d_ws;
    size_t off = 0;
    auto alloc = [&](size_t bytes)->void*{
        void* pp = ws + off;
        off += (bytes + 255) & ~(size_t)255;
        return pp;
    };
    unsigned short* hcb  = (unsigned short*)alloc((size_t)G*256*2);  // 10.24 MB
    float* hlin = (float*)alloc((size_t)G*64*4);                      // 5.12 MB
    float* es1  = (float*)alloc((size_t)G*4*4);
    float* ed1  = (float*)alloc((size_t)G*4*4);
    float* hh2  = (float*)alloc((size_t)G*4*4);
    float* es2  = (float*)alloc((size_t)G*4*4);
    float* ed2  = (float*)alloc((size_t)G*4*4);
    float* lv   = (float*)alloc((size_t)G*4);
    float* feat = (float*)alloc((size_t)G*4);
    unsigned short* hidbf = (unsigned short*)alloc((size_t)128*KA2*2);
    unsigned short* Abf1  = (unsigned short*)alloc((size_t)128*KA1*2);   // 5.1 MB
    // union: gemm1 partials (16.8 MB) then gemm2 partials (41 MB); stream-ordered
    float* part = (float*)alloc((size_t)KSPLIT2*P2STRIDE*4);             // 41 MB
    float* part2 = part;
    int*   cnt  = (int*)alloc((size_t)G*4);
    int*   offs = (int*)alloc((size_t)(G+1)*4);
    int*   cur  = (int*)alloc((size_t)G*4);
    int*   csr  = (int*)alloc((size_t)E_EDGES*4);

    hipMemsetAsync(cnt, 0, (size_t)G*4, stream);

    k_hist   <<<(E_EDGES+255)/256, 256, 0, stream>>>(ei, cnt);
    k_scan   <<<1, 1024, 0, stream>>>(cnt, offs, cur);
    k_scatter<<<(E_EDGES+255)/256, 256, 0, stream>>>(ei, cur, csr);

    k_hc   <<<(G + ROWS_HC - 1)/ROWS_HC, 320, 0, stream>>>(x, pos, ge, c1W, l1W, c1as, c1ad,
                                         hcb, hlin, es1, ed1);
    k_gat1 <<<G/4, 256, 0, stream>>>(hcb, hlin, es1, ed1, offs, csr, c1b, l1b,
                                     c2W, c2as, c2ad, l2W, hh2, es2, ed2, lv);
    k_gat2 <<<G, 64, 0, stream>>>(hh2, es2, ed2, offs, csr, lv, c2b, l2b, feat);

    dim3 gp(79, 128);
    k_prepA<<<gp, 256, 0, stream>>>(ctrl, feat, Abf1);
    k_pert <<<BATCH, 128, 0, stream>>>(pert, pW1, pb1, pW2, pb2, Abf1);

    dim3 g1(16, KSPLIT1);
    k_gemm1m<<<g1, 256, 0, stream>>>(Abf1, prW1, part);
    dim3 gr(128, 4);
    k_reduce<<<gr, 256, 0, stream>>>(part, prb1, hidbf);
    dim3 g2(626, KSPLIT2);
    k_gemm2m<<<g2, 256, 0, stream>>>(hidbf, prW2, part2);
    dim3 gr2(128, 79);
    k_reduce2<<<gr2, 256, 0, stream>>>(part2, prb2, out);
}